// Round 1
// baseline (4251.189 us; speedup 1.0000x reference)
//
#include <hip/hip_runtime.h>
#include <hip/hip_bf16.h>
#include <math.h>

#define BB 4
#define NN 1437
#define SS 56
#define PP 28
#define FIN 10
#define FFUT 6
#define HH 64
#define NBLK 2
#define TOPK 5
#define DD (SS*HH)     /* 3584 */
#define FD (PP*HH)     /* 1792 */
#define TOT (DD+FD)    /* 5376 */

__device__ __forceinline__ float gelu_exact(float x){
    return 0.5f*x*(1.0f+erff(x*0.70710678118654752440f));
}
__device__ __forceinline__ float wave_sum64(float v){
    #pragma unroll
    for (int o=1;o<64;o<<=1) v += __shfl_xor(v,o,64);
    return v;
}

// ---------------- emb norm: emb / max(||emb||,1e-12) ----------------
__global__ __launch_bounds__(64) void k_embnorm(const float* __restrict__ emb,
                                                float* __restrict__ out){
    int n = blockIdx.x; int l = threadIdx.x;
    float v = emb[(size_t)n*HH+l];
    float ss = wave_sum64(v*v);
    float nrm = fmaxf(sqrtf(ss), 1e-12f);
    out[(size_t)n*HH+l] = v/nrm;
}

// ------- front: h = LN(x@fp_w^T+fp_b)+embn ; ctx = sum_s h*rw[s] -------
__global__ __launch_bounds__(256) void k_front(
    const float* __restrict__ x, const float* __restrict__ fpw, const float* __restrict__ fpb,
    const float* __restrict__ lng, const float* __restrict__ lnb,
    const float* __restrict__ embn, float* __restrict__ h, float* __restrict__ ctx)
{
    int bn = blockIdx.x; int n = bn % NN;
    int tid=threadIdx.x; int lane=tid&63; int wv=tid>>6;
    __shared__ float xin[SS*FIN];
    __shared__ float wlds[HH*FIN];
    __shared__ float rw[SS];
    __shared__ float rsum;
    __shared__ float red[4][HH];
    for (int i=tid;i<SS*FIN;i+=256) xin[i]=x[(size_t)bn*SS*FIN+i];
    for (int i=tid;i<HH*FIN;i+=256) wlds[i]=fpw[i];
    if (tid<SS) rw[tid]=expf(-(float)(SS-tid)/14.0f);
    __syncthreads();
    if (tid==0){ float s=0.f; for(int i=0;i<SS;++i) s+=rw[i]; rsum=s; }
    __syncthreads();
    float inv_rs = 1.0f/rsum;
    float gg=lng[lane], bv=lnb[lane], el=embn[(size_t)n*HH+lane], fb0=fpb[lane];
    float cacc=0.f;
    for (int s=wv;s<SS;s+=4){
        float v=fb0;
        #pragma unroll
        for (int c=0;c<FIN;++c) v += xin[s*FIN+c]*wlds[lane*FIN+c];
        float m = wave_sum64(v)*(1.f/HH);
        float d = v-m;
        float va = wave_sum64(d*d)*(1.f/HH);
        float hn = d*rsqrtf(va+1e-5f)*gg + bv + el;
        h[((size_t)bn*SS+s)*HH+lane]=hn;
        cacc += hn * rw[s]*inv_rs;
    }
    red[wv][lane]=cacc;
    __syncthreads();
    if (wv==0) ctx[(size_t)bn*HH+lane]=red[0][lane]+red[1][lane]+red[2][lane]+red[3][lane];
}

// ---------------- Q/K projections ----------------
__global__ __launch_bounds__(64) void k_qk(
    const float* __restrict__ ctx, const float* __restrict__ qw, const float* __restrict__ qb,
    const float* __restrict__ kw, const float* __restrict__ kb,
    float* __restrict__ Q, float* __restrict__ K)
{
    __shared__ float wq[HH*65];
    __shared__ float wk2[HH*65];
    int lane=threadIdx.x; int bn=blockIdx.x;
    for (int i=lane;i<HH*HH;i+=64){ int hh=i>>6, kk=i&63; wq[kk*65+hh]=qw[i]; wk2[kk*65+hh]=kw[i]; }
    __syncthreads();
    const float* c = ctx + (size_t)bn*HH;
    float q=qb[lane], k=kb[lane];
    for (int kk=0;kk<HH;++kk){ float cv=c[kk]; q+=cv*wq[kk*65+lane]; k+=cv*wk2[kk*65+lane]; }
    Q[(size_t)bn*HH+lane]=q; K[(size_t)bn*HH+lane]=k;
}

// ------- comb row: da, clip/relu, top-5, softmax, blend, L1 normalize -------
__global__ __launch_bounds__(256) void k_comb(
    const float* __restrict__ Q, const float* __restrict__ K,
    const float* __restrict__ adj, const float* __restrict__ galpha,
    float* __restrict__ comb)
{
    int m=blockIdx.x, b=blockIdx.y, tid=threadIdx.x;
    __shared__ __align__(16) float qv[HH];
    __shared__ float row[NN];
    __shared__ float redv[256];
    __shared__ int   redi[256];
    __shared__ float selv[TOPK];
    __shared__ int   seli[TOPK];
    __shared__ float sden;
    if (tid<HH) qv[tid]=Q[((size_t)b*NN+m)*HH+tid];
    __syncthreads();
    for (int n=tid;n<NN;n+=256){
        const float4* kr=reinterpret_cast<const float4*>(K+((size_t)b*NN+n)*HH);
        const float4* q4=reinterpret_cast<const float4*>(qv);
        float d=0.f;
        #pragma unroll
        for (int t=0;t<16;++t){
            float4 kv=kr[t], qq=q4[t];
            d += kv.x*qq.x+kv.y*qq.y+kv.z*qq.z+kv.w*qq.w;
        }
        d*=0.125f;
        d=fminf(fmaxf(d,-10.f),10.f);
        d=fmaxf(d,0.f);
        row[n]=d;
    }
    __syncthreads();
    for (int it=0;it<TOPK;++it){
        float bv=-1e30f; int bi=NN;
        for (int n=tid;n<NN;n+=256){
            float v=row[n];
            if (v>bv||(v==bv&&n<bi)){bv=v;bi=n;}
        }
        redv[tid]=bv; redi[tid]=bi;
        __syncthreads();
        for (int off=128;off>0;off>>=1){
            if (tid<off){
                float v2=redv[tid+off]; int i2=redi[tid+off];
                if (v2>redv[tid]||(v2==redv[tid]&&i2<redi[tid])){redv[tid]=v2;redi[tid]=i2;}
            }
            __syncthreads();
        }
        if (tid==0){ selv[it]=redv[0]; seli[it]=redi[0]; row[redi[0]]=-1e30f; }
        __syncthreads();
    }
    if (tid==0){
        float mx=selv[0], s=0.f;
        for (int j=0;j<TOPK;++j) s+=expf(selv[j]-mx);
        sden=s;
    }
    __syncthreads();
    float alpha=1.f/(1.f+expf(-galpha[0]));
    float mx=selv[0], sd=sden;
    float part=0.f;
    for (int n=tid;n<NN;n+=256){
        float v=alpha*adj[(size_t)m*NN+n];
        #pragma unroll
        for (int j=0;j<TOPK;++j) if (n==seli[j]) v += (1.f-alpha)*expf(selv[j]-mx)/sd;
        row[n]=v;
        part+=fabsf(v);
    }
    redv[tid]=part;
    __syncthreads();
    for (int off=128;off>0;off>>=1){
        if (tid<off) redv[tid]+=redv[tid+off];
        __syncthreads();
    }
    float inv=1.f/fmaxf(redv[0],1e-12f);
    for (int n=tid;n<NN;n+=256) comb[((size_t)b*NN+m)*NN+n]=row[n]*inv;
}

// ---------------- fused mixer block (everything except spatial bmm) ----------------
__device__ __forceinline__ void ln_rows(const float* xl, float* xn,
        const float* __restrict__ g, const float* __restrict__ bwt, int lane, int wv){
    float gg=g[lane], bv=bwt[lane];
    for (int s=wv;s<SS;s+=4){
        float v = xl[s*HH+lane];
        float m = wave_sum64(v) * (1.0f/HH);
        float d = v - m;
        float va = wave_sum64(d*d) * (1.0f/HH);
        xn[s*HH+lane] = d*rsqrtf(va+1e-5f)*gg + bv;
    }
}

__global__ __launch_bounds__(256) void k_mixer(
    float* __restrict__ h, float* __restrict__ xp,
    const float* __restrict__ wk, const float* __restrict__ mk,
    const float* __restrict__ lncg, const float* __restrict__ lncb,
    const float* __restrict__ lntg, const float* __restrict__ lntb,
    const float* __restrict__ lnfg, const float* __restrict__ lnfb,
    const float* __restrict__ lnsg, const float* __restrict__ lnsb,
    const float* __restrict__ tw, const float* __restrict__ tb,
    const float* __restrict__ fw, const float* __restrict__ fb,
    const float* __restrict__ sw)
{
    int bn = blockIdx.x; int tid = threadIdx.x; int lane = tid&63; int wv = tid>>6;
    __shared__ float xl[SS*HH];
    __shared__ float xn[SS*HH];
    __shared__ float wl[HH*65];
    __shared__ float cw[35];
    __shared__ float tbl[SS];
    float* base = h + (size_t)bn*SS*HH;
    for (int i=tid;i<SS*HH;i+=256) xl[i]=base[i];
    if (tid<7) cw[tid]=wk[tid];
    if (tid>=16 && tid<44) cw[7+tid-16]=mk[tid-16];
    if (tid>=64 && tid<64+SS) tbl[tid-64]=tb[tid-64];
    __syncthreads();
    // ---- conv branch ----
    ln_rows(xl,xn,lncg,lncb,lane,wv);
    __syncthreads();
    for (int p=tid;p<SS*HH;p+=256){
        int s=p>>6, f=p&63;
        float acc=0.f;
        #pragma unroll
        for (int k=0;k<7;++k){int s2=s-3+k; if(s2>=0&&s2<SS) acc+=xn[s2*HH+f]*cw[k];}
        #pragma unroll
        for (int k=0;k<28;++k){int s2=s-13+k; if(s2>=0&&s2<SS) acc+=xn[s2*HH+f]*cw[7+k];}
        xl[p]+=acc;
    }
    __syncthreads();
    // ---- temporal MLP ----
    ln_rows(xl,xn,lntg,lntb,lane,wv);
    for (int i=tid;i<SS*SS;i+=256) wl[(i/SS)*65+(i%SS)]=tw[i];
    __syncthreads();
    for (int p=tid;p<SS*HH;p+=256){
        int s=p>>6, f=p&63;
        float acc=tbl[s];
        for (int sp=0;sp<SS;++sp) acc += xn[sp*HH+f]*wl[s*65+sp];
        xl[p]+=gelu_exact(acc);
    }
    __syncthreads();
    // ---- feature MLP ----
    ln_rows(xl,xn,lnfg,lnfb,lane,wv);
    for (int i=tid;i<HH*HH;i+=256) wl[(i>>6)*65+(i&63)]=fw[i];
    __syncthreads();
    for (int p=tid;p<SS*HH;p+=256){
        int s=p>>6, f=p&63;
        float acc=fb[f];
        #pragma unroll 8
        for (int fp=0;fp<HH;++fp) acc += xn[s*HH+fp]*wl[f*65+fp];
        xl[p]+=gelu_exact(acc);
    }
    __syncthreads();
    // ---- spatial projection + writeback ----
    ln_rows(xl,xn,lnsg,lnsb,lane,wv);
    for (int i=tid;i<HH*HH;i+=256) wl[(i>>6)*65+(i&63)]=sw[i];
    __syncthreads();
    float* xpb = xp + (size_t)bn*SS*HH;
    for (int p=tid;p<SS*HH;p+=256){
        int s=p>>6, f=p&63;
        float acc=0.f;
        #pragma unroll 8
        for (int fp=0;fp<HH;++fp) acc += xn[s*HH+fp]*wl[f*65+fp];
        xpb[p]=acc;
        base[p]=xl[p];
    }
}

// ---------------- spatial bmm: h[b] += comb[b] @ xp[b] + sb ----------------
__global__ __launch_bounds__(256) void k_bmm(
    const float* __restrict__ comb, const float* __restrict__ xp,
    const float* __restrict__ sb, float* __restrict__ h)
{
    int bm=blockIdx.x, bd=blockIdx.y, b=blockIdx.z;
    int tid=threadIdx.x, tr=tid>>4, tc=tid&15;
    __shared__ __align__(16) float Ast[32*68];
    __shared__ __align__(16) float Bs[32*68];
    float acc[4][4]={};
    int m0=bm*64, d0=bd*64;
    const float* A = comb + (size_t)b*NN*NN;
    const float* X = xp + (size_t)b*NN*DD;
    for (int k0=0;k0<NN;k0+=32){
        #pragma unroll
        for (int j=0;j<8;++j){
            int idx=tid+j*256; int ki=idx&31, mi=idx>>5;
            int m=m0+mi, k=k0+ki;
            Ast[ki*68+mi] = (m<NN && k<NN) ? A[(size_t)m*NN+k] : 0.f;
        }
        #pragma unroll
        for (int j=0;j<8;++j){
            int idx=tid+j*256; int di=idx&63, ki=idx>>6;
            int k=k0+ki;
            Bs[ki*68+di] = (k<NN) ? X[(size_t)k*DD + d0+di] : 0.f;
        }
        __syncthreads();
        #pragma unroll
        for (int kk=0;kk<32;++kk){
            const float4 av  = *reinterpret_cast<const float4*>(&Ast[kk*68+tr*4]);
            const float4 bv4 = *reinterpret_cast<const float4*>(&Bs[kk*68+tc*4]);
            float a4[4]={av.x,av.y,av.z,av.w};
            float b4[4]={bv4.x,bv4.y,bv4.z,bv4.w};
            #pragma unroll
            for (int i=0;i<4;++i)
                #pragma unroll
                for (int j=0;j<4;++j) acc[i][j]+=a4[i]*b4[j];
        }
        __syncthreads();
    }
    #pragma unroll
    for (int i=0;i<4;++i){
        int m=m0+tr*4+i;
        if (m<NN){
            size_t rb=((size_t)b*NN+m)*DD + d0;
            #pragma unroll
            for (int j=0;j<4;++j){
                int f=tc*4+j;
                h[rb+f] += acc[i][j] + sb[f];
            }
        }
    }
}

// ---------------- head: future proj + feats @ head_w^T + head_b ----------------
__global__ __launch_bounds__(256) void k_head(
    const float* __restrict__ h, const float* __restrict__ xf,
    const float* __restrict__ fw, const float* __restrict__ fbias,
    const float* __restrict__ hw, const float* __restrict__ hb,
    float* __restrict__ out)
{
    int bn=blockIdx.x; int tid=threadIdx.x; int lane=tid&63; int wv=tid>>6;
    __shared__ float fut[FD];
    __shared__ float fwl[HH*FFUT];
    __shared__ float fbl[HH];
    __shared__ float xfl[PP*FFUT];
    __shared__ float red[4][PP];
    for (int i=tid;i<HH*FFUT;i+=256) fwl[i]=fw[i];
    if (tid<HH) fbl[tid]=fbias[tid];
    for (int i=tid;i<PP*FFUT;i+=256) xfl[i]=xf[(size_t)bn*PP*FFUT+i];
    __syncthreads();
    for (int q=tid;q<FD;q+=256){
        int pp=q>>6, hh2=q&63;
        float v=fbl[hh2];
        #pragma unroll
        for (int c=0;c<FFUT;++c) v += xfl[pp*FFUT+c]*fwl[hh2*FFUT+c];
        fut[q]=v;
    }
    __syncthreads();
    float acc[PP];
    #pragma unroll
    for (int p=0;p<PP;++p) acc[p]=0.f;
    const float* hrow = h + (size_t)bn*DD;
    for (int d=tid; d<TOT; d+=256){
        float v = (d<DD)?hrow[d]:fut[d-DD];
        #pragma unroll
        for (int p=0;p<PP;++p) acc[p] += v*hw[(size_t)p*TOT+d];
    }
    #pragma unroll
    for (int p=0;p<PP;++p){
        float a=wave_sum64(acc[p]);
        if (lane==0) red[wv][p]=a;
    }
    __syncthreads();
    if (tid<PP) out[(size_t)bn*PP+tid] = red[0][tid]+red[1][tid]+red[2][tid]+red[3][tid] + hb[tid];
}

extern "C" void kernel_launch(void* const* d_in, const int* in_sizes, int n_in,
                              void* d_out, int out_size, void* d_ws, size_t ws_size,
                              hipStream_t stream)
{
    const float* x      = (const float*)d_in[0];
    const float* xfut   = (const float*)d_in[1];
    const float* adj    = (const float*)d_in[2];
    const float* fp_w   = (const float*)d_in[3];
    const float* fp_b   = (const float*)d_in[4];
    const float* inlng  = (const float*)d_in[5];
    const float* inlnb  = (const float*)d_in[6];
    const float* q_w    = (const float*)d_in[7];
    const float* q_b    = (const float*)d_in[8];
    const float* k_w    = (const float*)d_in[9];
    const float* k_b    = (const float*)d_in[10];
    const float* nemb   = (const float*)d_in[11];
    const float* galpha = (const float*)d_in[12];
    const float* wk     = (const float*)d_in[13];
    const float* mk     = (const float*)d_in[14];
    const float* lncg   = (const float*)d_in[15];
    const float* lncb   = (const float*)d_in[16];
    const float* lntg   = (const float*)d_in[17];
    const float* lntb   = (const float*)d_in[18];
    const float* lnfg   = (const float*)d_in[19];
    const float* lnfb   = (const float*)d_in[20];
    const float* lnsg   = (const float*)d_in[21];
    const float* lnsb   = (const float*)d_in[22];
    const float* tw     = (const float*)d_in[23];
    const float* tb     = (const float*)d_in[24];
    const float* fw     = (const float*)d_in[25];
    const float* fb     = (const float*)d_in[26];
    const float* sw     = (const float*)d_in[27];
    const float* sb     = (const float*)d_in[28];
    const float* futw   = (const float*)d_in[29];
    const float* futb   = (const float*)d_in[30];
    const float* hw     = (const float*)d_in[31];
    const float* hb     = (const float*)d_in[32];
    (void)in_sizes; (void)n_in; (void)out_size; (void)ws_size;
    float* out = (float*)d_out;
    float* ws = (float*)d_ws;
    const size_t HSZ = (size_t)BB*NN*SS*HH;     // 20,600,832 floats
    const size_t CSZ = (size_t)BB*NN*NN;        //  8,259,876 floats
    float* h    = ws;
    float* xp   = h + HSZ;
    float* comb = xp + HSZ;
    float* embn = comb + CSZ;
    float* ctx  = embn + (size_t)NN*HH;
    float* Q    = ctx + (size_t)BB*NN*HH;
    float* K    = Q + (size_t)BB*NN*HH;

    k_embnorm<<<NN,64,0,stream>>>(nemb, embn);
    k_front<<<BB*NN,256,0,stream>>>(x, fp_w, fp_b, inlng, inlnb, embn, h, ctx);
    k_qk<<<BB*NN,64,0,stream>>>(ctx, q_w,q_b,k_w,k_b,Q,K);
    dim3 gcomb(NN,BB);
    k_comb<<<gcomb,256,0,stream>>>(Q,K,adj,galpha,comb);
    dim3 gbmm((NN+63)/64, DD/64, BB);
    for (int i=0;i<NBLK;++i){
        k_mixer<<<BB*NN,256,0,stream>>>(h,xp, wk+i*7, mk+i*28,
            lncg+i*HH,lncb+i*HH, lntg+i*HH,lntb+i*HH, lnfg+i*HH,lnfb+i*HH, lnsg+i*HH,lnsb+i*HH,
            tw+i*SS*SS, tb+i*SS, fw+i*HH*HH, fb+i*HH, sw+i*HH*HH);
        k_bmm<<<gbmm,256,0,stream>>>(comb, xp, sb+i*HH, h);
    }
    k_head<<<BB*NN,256,0,stream>>>(h, xfut, futw, futb, hw, hb, out);
}

// Round 2
// 2127.233 us; speedup vs baseline: 1.9985x; 1.9985x over previous
//
#include <hip/hip_runtime.h>
#include <hip/hip_bf16.h>
#include <math.h>

#define BB 4
#define NN 1437
#define SS 56
#define PP 28
#define FIN 10
#define FFUT 6
#define HH 64
#define NBLK 2
#define TOPK 5
#define DD (SS*HH)     /* 3584 */
#define FD (PP*HH)     /* 1792 */
#define TOT (DD+FD)    /* 5376 */
#define MP 1536        /* padded M (12*128) */
#define KP 1472        /* padded K (46*32)  */
#define NT (KP/32)     /* 46 K-steps */

typedef __attribute__((ext_vector_type(8))) __bf16 bf16x8;
typedef __attribute__((ext_vector_type(4))) float  f32x4;

__device__ __forceinline__ float gelu_exact(float x){
    return 0.5f*x*(1.0f+erff(x*0.70710678118654752440f));
}
__device__ __forceinline__ float wave_sum64(float v){
    #pragma unroll
    for (int o=1;o<64;o<<=1) v += __shfl_xor(v,o,64);
    return v;
}
__device__ __forceinline__ void async_load16(const void* g, void* l){
    __builtin_amdgcn_global_load_lds(
        (const __attribute__((address_space(1))) void*)g,
        (__attribute__((address_space(3))) void*)l, 16, 0, 0);
}

// ---------------- emb norm ----------------
__global__ __launch_bounds__(64) void k_embnorm(const float* __restrict__ emb,
                                                float* __restrict__ out){
    int n = blockIdx.x; int l = threadIdx.x;
    float v = emb[(size_t)n*HH+l];
    float ss = wave_sum64(v*v);
    float nrm = fmaxf(sqrtf(ss), 1e-12f);
    out[(size_t)n*HH+l] = v/nrm;
}

// ------- front: h = LN(x@fp_w^T+fp_b)+embn ; ctx = recency ctx -------
__global__ __launch_bounds__(256) void k_front(
    const float* __restrict__ x, const float* __restrict__ fpw, const float* __restrict__ fpb,
    const float* __restrict__ lng, const float* __restrict__ lnb,
    const float* __restrict__ embn, float* __restrict__ h, float* __restrict__ ctx)
{
    int bn = blockIdx.x; int n = bn % NN;
    int tid=threadIdx.x; int lane=tid&63; int wv=tid>>6;
    __shared__ float xin[SS*FIN];
    __shared__ float wlds[HH*FIN];
    __shared__ float rw[SS];
    __shared__ float rsum;
    __shared__ float red[4][HH];
    for (int i=tid;i<SS*FIN;i+=256) xin[i]=x[(size_t)bn*SS*FIN+i];
    for (int i=tid;i<HH*FIN;i+=256) wlds[i]=fpw[i];
    if (tid<SS) rw[tid]=expf(-(float)(SS-tid)/14.0f);
    __syncthreads();
    if (tid==0){ float s=0.f; for(int i=0;i<SS;++i) s+=rw[i]; rsum=s; }
    __syncthreads();
    float inv_rs = 1.0f/rsum;
    float gg=lng[lane], bv=lnb[lane], el=embn[(size_t)n*HH+lane], fb0=fpb[lane];
    float cacc=0.f;
    for (int s=wv;s<SS;s+=4){
        float v=fb0;
        #pragma unroll
        for (int c=0;c<FIN;++c) v += xin[s*FIN+c]*wlds[lane*FIN+c];
        float m = wave_sum64(v)*(1.f/HH);
        float d = v-m;
        float va = wave_sum64(d*d)*(1.f/HH);
        float hn = d*rsqrtf(va+1e-5f)*gg + bv + el;
        h[((size_t)bn*SS+s)*HH+lane]=hn;
        cacc += hn * rw[s]*inv_rs;
    }
    red[wv][lane]=cacc;
    __syncthreads();
    if (wv==0) ctx[(size_t)bn*HH+lane]=red[0][lane]+red[1][lane]+red[2][lane]+red[3][lane];
}

// ---------------- Q/K projections ----------------
__global__ __launch_bounds__(64) void k_qk(
    const float* __restrict__ ctx, const float* __restrict__ qw, const float* __restrict__ qb,
    const float* __restrict__ kw, const float* __restrict__ kb,
    float* __restrict__ Q, float* __restrict__ K)
{
    __shared__ float wq[HH*65];
    __shared__ float wk2[HH*65];
    int lane=threadIdx.x; int bn=blockIdx.x;
    for (int i=lane;i<HH*HH;i+=64){ int hh=i>>6, kk=i&63; wq[kk*65+hh]=qw[i]; wk2[kk*65+hh]=kw[i]; }
    __syncthreads();
    const float* c = ctx + (size_t)bn*HH;
    float q=qb[lane], k=kb[lane];
    for (int kk=0;kk<HH;++kk){ float cv=c[kk]; q+=cv*wq[kk*65+lane]; k+=cv*wk2[kk*65+lane]; }
    Q[(size_t)bn*HH+lane]=q; K[(size_t)bn*HH+lane]=k;
}

// ------- comb row → bf16 padded A matrix [MP][KP] -------
__global__ __launch_bounds__(256) void k_comb(
    const float* __restrict__ Q, const float* __restrict__ K,
    const float* __restrict__ adj, const float* __restrict__ galpha,
    __hip_bfloat16* __restrict__ combh)
{
    int m=blockIdx.x, b=blockIdx.y, tid=threadIdx.x;
    __shared__ __align__(16) float qv[HH];
    __shared__ float row[NN];
    __shared__ float redv[256];
    __shared__ int   redi[256];
    __shared__ float selv[TOPK];
    __shared__ int   seli[TOPK];
    __shared__ float sden;
    if (tid<HH) qv[tid]=Q[((size_t)b*NN+m)*HH+tid];
    __syncthreads();
    for (int n=tid;n<NN;n+=256){
        const float4* kr=reinterpret_cast<const float4*>(K+((size_t)b*NN+n)*HH);
        const float4* q4=reinterpret_cast<const float4*>(qv);
        float d=0.f;
        #pragma unroll
        for (int t=0;t<16;++t){
            float4 kv=kr[t], qq=q4[t];
            d += kv.x*qq.x+kv.y*qq.y+kv.z*qq.z+kv.w*qq.w;
        }
        d*=0.125f;
        d=fminf(fmaxf(d,-10.f),10.f);
        d=fmaxf(d,0.f);
        row[n]=d;
    }
    __syncthreads();
    for (int it=0;it<TOPK;++it){
        float bv=-1e30f; int bi=NN;
        for (int n=tid;n<NN;n+=256){
            float v=row[n];
            if (v>bv||(v==bv&&n<bi)){bv=v;bi=n;}
        }
        redv[tid]=bv; redi[tid]=bi;
        __syncthreads();
        for (int off=128;off>0;off>>=1){
            if (tid<off){
                float v2=redv[tid+off]; int i2=redi[tid+off];
                if (v2>redv[tid]||(v2==redv[tid]&&i2<redi[tid])){redv[tid]=v2;redi[tid]=i2;}
            }
            __syncthreads();
        }
        if (tid==0){ selv[it]=redv[0]; seli[it]=redi[0]; row[redi[0]]=-1e30f; }
        __syncthreads();
    }
    if (tid==0){
        float mx=selv[0], s=0.f;
        for (int j=0;j<TOPK;++j) s+=expf(selv[j]-mx);
        sden=s;
    }
    __syncthreads();
    float alpha=1.f/(1.f+expf(-galpha[0]));
    float mx=selv[0], sd=sden;
    float part=0.f;
    for (int n=tid;n<NN;n+=256){
        float v=alpha*adj[(size_t)m*NN+n];
        #pragma unroll
        for (int j=0;j<TOPK;++j) if (n==seli[j]) v += (1.f-alpha)*expf(selv[j]-mx)/sd;
        row[n]=v;
        part+=fabsf(v);
    }
    redv[tid]=part;
    __syncthreads();
    for (int off=128;off>0;off>>=1){
        if (tid<off) redv[tid]+=redv[tid+off];
        __syncthreads();
    }
    float inv=1.f/fmaxf(redv[0],1e-12f);
    __hip_bfloat16* dst = combh + ((size_t)b*MP+m)*KP;
    for (int n=tid;n<KP;n+=256){
        float v = (n<NN) ? row[n]*inv : 0.f;
        dst[n]=__float2bfloat16(v);
    }
}

// ---------------- fused mixer block ----------------
__device__ __forceinline__ void ln_rows(const float* xl, float* xn,
        const float* __restrict__ g, const float* __restrict__ bwt, int lane, int wv){
    float gg=g[lane], bv=bwt[lane];
    for (int s=wv;s<SS;s+=4){
        float v = xl[s*HH+lane];
        float m = wave_sum64(v) * (1.0f/HH);
        float d = v - m;
        float va = wave_sum64(d*d) * (1.0f/HH);
        xn[s*HH+lane] = d*rsqrtf(va+1e-5f)*gg + bv;
    }
}

__global__ __launch_bounds__(256) void k_mixer(
    float* __restrict__ h, __hip_bfloat16* __restrict__ xpb,
    const float* __restrict__ wk, const float* __restrict__ mk,
    const float* __restrict__ lncg, const float* __restrict__ lncb,
    const float* __restrict__ lntg, const float* __restrict__ lntb,
    const float* __restrict__ lnfg, const float* __restrict__ lnfb,
    const float* __restrict__ lnsg, const float* __restrict__ lnsb,
    const float* __restrict__ tw, const float* __restrict__ tb,
    const float* __restrict__ fw, const float* __restrict__ fb,
    const float* __restrict__ sw)
{
    int bn = blockIdx.x; int tid = threadIdx.x; int lane = tid&63; int wv = tid>>6;
    __shared__ float xl[SS*HH];
    __shared__ float xn[SS*HH];
    __shared__ float wl[HH*65];
    __shared__ float cw[35];
    __shared__ float tbl[SS];
    float* base = h + (size_t)bn*SS*HH;
    for (int i=tid;i<SS*HH;i+=256) xl[i]=base[i];
    if (tid<7) cw[tid]=wk[tid];
    if (tid>=16 && tid<44) cw[7+tid-16]=mk[tid-16];
    if (tid>=64 && tid<64+SS) tbl[tid-64]=tb[tid-64];
    __syncthreads();
    // ---- conv branch ----
    ln_rows(xl,xn,lncg,lncb,lane,wv);
    __syncthreads();
    for (int p=tid;p<SS*HH;p+=256){
        int s=p>>6, f=p&63;
        float acc=0.f;
        #pragma unroll
        for (int k=0;k<7;++k){int s2=s-3+k; if(s2>=0&&s2<SS) acc+=xn[s2*HH+f]*cw[k];}
        #pragma unroll
        for (int k=0;k<28;++k){int s2=s-13+k; if(s2>=0&&s2<SS) acc+=xn[s2*HH+f]*cw[7+k];}
        xl[p]+=acc;
    }
    __syncthreads();
    // ---- temporal MLP ----
    ln_rows(xl,xn,lntg,lntb,lane,wv);
    for (int i=tid;i<SS*SS;i+=256) wl[(i/SS)*65+(i%SS)]=tw[i];
    __syncthreads();
    for (int p=tid;p<SS*HH;p+=256){
        int s=p>>6, f=p&63;
        float acc=tbl[s];
        for (int sp=0;sp<SS;++sp) acc += xn[sp*HH+f]*wl[s*65+sp];
        xl[p]+=gelu_exact(acc);
    }
    __syncthreads();
    // ---- feature MLP ----
    ln_rows(xl,xn,lnfg,lnfb,lane,wv);
    for (int i=tid;i<HH*HH;i+=256) wl[(i>>6)*65+(i&63)]=fw[i];
    __syncthreads();
    for (int p=tid;p<SS*HH;p+=256){
        int s=p>>6, f=p&63;
        float acc=fb[f];
        #pragma unroll 8
        for (int fp=0;fp<HH;++fp) acc += xn[s*HH+fp]*wl[f*65+fp];
        xl[p]+=gelu_exact(acc);
    }
    __syncthreads();
    // ---- spatial projection + writeback ----
    ln_rows(xl,xn,lnsg,lnsb,lane,wv);
    for (int i=tid;i<HH*HH;i+=256) wl[(i>>6)*65+(i&63)]=sw[i];
    __syncthreads();
    __hip_bfloat16* xpo = xpb + (size_t)bn*SS*HH;
    for (int p=tid;p<SS*HH;p+=256){
        int s=p>>6, f=p&63;
        float acc=0.f;
        #pragma unroll 8
        for (int fp=0;fp<HH;++fp) acc += xn[s*HH+fp]*wl[f*65+fp];
        xpo[p]=__float2bfloat16(acc);
        base[p]=xl[p];
    }
}

// ---- pack xp bf16 [N][D] -> MFMA-ready [KP/8][D][8] with K zero-pad ----
__global__ __launch_bounds__(256) void k_pack_xp(
    const __hip_bfloat16* __restrict__ xpb, __hip_bfloat16* __restrict__ xpg)
{
    int d = blockIdx.x*256 + threadIdx.x;
    int kc = blockIdx.y; int b = blockIdx.z;
    union { __hip_bfloat16 hv[8]; float4 f4; } u;
    #pragma unroll
    for (int j=0;j<8;++j){
        int k = kc*8+j;
        u.hv[j] = (k<NN) ? xpb[((size_t)b*NN+k)*DD + d] : __float2bfloat16(0.f);
    }
    *reinterpret_cast<float4*>(&xpg[(((size_t)b*(KP/8)+kc)*DD + d)*8]) = u.f4;
}

// ---------------- spatial bmm via MFMA: h[b] += comb[b] @ xp[b] + sb ----------------
__global__ __launch_bounds__(256) void k_bmm_mfma(
    const __hip_bfloat16* __restrict__ combh,  // [B][MP][KP] row-major, zero-padded
    const __hip_bfloat16* __restrict__ xpg,    // [B][KP/8][D][8] packed, zero-padded
    const float* __restrict__ sb,
    float* __restrict__ h)                     // [B][N][D] f32, accumulated
{
    int bm=blockIdx.x, bd=blockIdx.y, b=blockIdx.z;
    int tid=threadIdx.x; int lane=tid&63; int wv=tid>>6;
    int m0=bm*128, d0=bd*128;
    __shared__ short As[2][4096];   // [kc(4)][r(128)][8]  8KB per buf
    __shared__ short Bs[2][4096];   // [kc(4)][d(128)][8]  8KB per buf

    const char* cb = (const char*)(combh + (size_t)b*MP*KP);
    const char* xb = (const char*)(xpg   + (size_t)b*(KP/8)*(size_t)DD*8);

    // per-lane staging source addresses (2 A-issues + 2 B-issues per wave)
    int ia0 = wv*2, ia1 = wv*2+1;
    int g0 = ia0*64 + lane, g1 = ia1*64 + lane;
    const char* srcA0 = cb + ((size_t)(m0 + (g0&127))*KP + (g0>>7)*8)*2;
    const char* srcA1 = cb + ((size_t)(m0 + (g1&127))*KP + (g1>>7)*8)*2;
    const char* srcB0 = xb + ((size_t)(g0>>7)*DD + d0 + (g0&127))*16;
    const char* srcB1 = xb + ((size_t)(g1>>7)*DD + d0 + (g1&127))*16;
    const size_t BSTEP = (size_t)4*DD*16;

    // fragment LDS offsets (in shorts)
    int wr=wv>>1, wc=wv&1;
    int aoff[4], boff[4];
    #pragma unroll
    for (int i=0;i<4;++i) aoff[i] = ((lane>>4)*128 + wr*64 + i*16 + (lane&15))*8;
    #pragma unroll
    for (int j=0;j<4;++j) boff[j] = ((lane>>4)*128 + wc*64 + j*16 + (lane&15))*8;

    f32x4 acc[4][4];
    #pragma unroll
    for (int i=0;i<4;++i)
        #pragma unroll
        for (int j=0;j<4;++j) acc[i][j]=(f32x4){0.f,0.f,0.f,0.f};

#define STAGE(CUR) do { \
    async_load16(srcA0, &As[CUR][ia0*512]); \
    async_load16(srcA1, &As[CUR][ia1*512]); \
    async_load16(srcB0, &Bs[CUR][ia0*512]); \
    async_load16(srcB1, &Bs[CUR][ia1*512]); \
    srcA0+=64; srcA1+=64; srcB0+=BSTEP; srcB1+=BSTEP; } while(0)

    STAGE(0);
    asm volatile("s_waitcnt vmcnt(0)");
    __syncthreads();
    int cur=0;
    for (int t=0;t<NT;++t){
        if (t+1<NT) STAGE(cur^1);
        const short* Ab=As[cur]; const short* Bb=Bs[cur];
        bf16x8 af[4], bfv[4];
        #pragma unroll
        for (int i=0;i<4;++i) af[i]=*reinterpret_cast<const bf16x8*>(Ab + aoff[i]);
        #pragma unroll
        for (int j=0;j<4;++j) bfv[j]=*reinterpret_cast<const bf16x8*>(Bb + boff[j]);
        #pragma unroll
        for (int i=0;i<4;++i)
            #pragma unroll
            for (int j=0;j<4;++j)
                acc[i][j]=__builtin_amdgcn_mfma_f32_16x16x32_bf16(af[i],bfv[j],acc[i][j],0,0,0);
        __syncthreads();
        cur^=1;
    }
#undef STAGE

    // epilogue: h += acc + sb
    int row0 = m0 + wr*64 + (lane>>4)*4;
    int colb = d0 + wc*64 + (lane&15);
    #pragma unroll
    for (int i=0;i<4;++i){
        #pragma unroll
        for (int q=0;q<4;++q){
            int m = row0 + i*16 + q;
            if (m < NN){
                size_t rb = ((size_t)b*NN+m)*DD;
                #pragma unroll
                for (int j=0;j<4;++j){
                    int d = colb + j*16;
                    h[rb+d] += acc[i][j][q] + sb[(lane&15)+j*16];
                }
            }
        }
    }
}

// ---------------- head ----------------
__global__ __launch_bounds__(256) void k_head(
    const float* __restrict__ h, const float* __restrict__ xf,
    const float* __restrict__ fw, const float* __restrict__ fbias,
    const float* __restrict__ hw, const float* __restrict__ hb,
    float* __restrict__ out)
{
    int bn=blockIdx.x; int tid=threadIdx.x; int lane=tid&63; int wv=tid>>6;
    __shared__ float fut[FD];
    __shared__ float fwl[HH*FFUT];
    __shared__ float fbl[HH];
    __shared__ float xfl[PP*FFUT];
    __shared__ float red[4][PP];
    for (int i=tid;i<HH*FFUT;i+=256) fwl[i]=fw[i];
    if (tid<HH) fbl[tid]=fbias[tid];
    for (int i=tid;i<PP*FFUT;i+=256) xfl[i]=xf[(size_t)bn*PP*FFUT+i];
    __syncthreads();
    for (int q=tid;q<FD;q+=256){
        int pp=q>>6, hh2=q&63;
        float v=fbl[hh2];
        #pragma unroll
        for (int c=0;c<FFUT;++c) v += xfl[pp*FFUT+c]*fwl[hh2*FFUT+c];
        fut[q]=v;
    }
    __syncthreads();
    float acc[PP];
    #pragma unroll
    for (int p=0;p<PP;++p) acc[p]=0.f;
    const float* hrow = h + (size_t)bn*DD;
    for (int d=tid; d<TOT; d+=256){
        float v = (d<DD)?hrow[d]:fut[d-DD];
        #pragma unroll
        for (int p=0;p<PP;++p) acc[p] += v*hw[(size_t)p*TOT+d];
    }
    #pragma unroll
    for (int p=0;p<PP;++p){
        float a=wave_sum64(acc[p]);
        if (lane==0) red[wv][p]=a;
    }
    __syncthreads();
    if (tid<PP) out[(size_t)bn*PP+tid] = red[0][tid]+red[1][tid]+red[2][tid]+red[3][tid] + hb[tid];
}

extern "C" void kernel_launch(void* const* d_in, const int* in_sizes, int n_in,
                              void* d_out, int out_size, void* d_ws, size_t ws_size,
                              hipStream_t stream)
{
    const float* x      = (const float*)d_in[0];
    const float* xfut   = (const float*)d_in[1];
    const float* adj    = (const float*)d_in[2];
    const float* fp_w   = (const float*)d_in[3];
    const float* fp_b   = (const float*)d_in[4];
    const float* inlng  = (const float*)d_in[5];
    const float* inlnb  = (const float*)d_in[6];
    const float* q_w    = (const float*)d_in[7];
    const float* q_b    = (const float*)d_in[8];
    const float* k_w    = (const float*)d_in[9];
    const float* k_b    = (const float*)d_in[10];
    const float* nemb   = (const float*)d_in[11];
    const float* galpha = (const float*)d_in[12];
    const float* wk     = (const float*)d_in[13];
    const float* mk     = (const float*)d_in[14];
    const float* lncg   = (const float*)d_in[15];
    const float* lncb   = (const float*)d_in[16];
    const float* lntg   = (const float*)d_in[17];
    const float* lntb   = (const float*)d_in[18];
    const float* lnfg   = (const float*)d_in[19];
    const float* lnfb   = (const float*)d_in[20];
    const float* lnsg   = (const float*)d_in[21];
    const float* lnsb   = (const float*)d_in[22];
    const float* tw     = (const float*)d_in[23];
    const float* tb     = (const float*)d_in[24];
    const float* fw     = (const float*)d_in[25];
    const float* fb     = (const float*)d_in[26];
    const float* sw     = (const float*)d_in[27];
    const float* sb     = (const float*)d_in[28];
    const float* futw   = (const float*)d_in[29];
    const float* futb   = (const float*)d_in[30];
    const float* hw     = (const float*)d_in[31];
    const float* hb     = (const float*)d_in[32];
    (void)in_sizes; (void)n_in; (void)out_size; (void)ws_size;
    float* out = (float*)d_out;
    float* ws = (float*)d_ws;
    const size_t HSZ = (size_t)BB*NN*SS*HH;     // 20,600,832

    float* h    = ws;
    float* embn = h + HSZ;
    float* ctx  = embn + (size_t)NN*HH;
    float* Q    = ctx + (size_t)BB*NN*HH;
    float* K    = Q + (size_t)BB*NN*HH;
    __hip_bfloat16* xpb   = (__hip_bfloat16*)(K + (size_t)BB*NN*HH);
    __hip_bfloat16* combh = xpb + HSZ;
    __hip_bfloat16* xpg   = combh + (size_t)BB*MP*KP;

    k_embnorm<<<NN,64,0,stream>>>(nemb, embn);
    k_front<<<BB*NN,256,0,stream>>>(x, fp_w, fp_b, inlng, inlnb, embn, h, ctx);
    k_qk<<<BB*NN,64,0,stream>>>(ctx, q_w,q_b,k_w,k_b,Q,K);
    hipMemsetAsync(combh, 0, (size_t)BB*MP*KP*sizeof(__hip_bfloat16), stream);
    dim3 gcomb(NN,BB);
    k_comb<<<gcomb,256,0,stream>>>(Q,K,adj,galpha,combh);
    dim3 gpack(DD/256, KP/8, BB);
    dim3 gbmm(MP/128, DD/128, BB);
    for (int i=0;i<NBLK;++i){
        k_mixer<<<BB*NN,256,0,stream>>>(h,xpb, wk+i*7, mk+i*28,
            lncg+i*HH,lncb+i*HH, lntg+i*HH,lntb+i*HH, lnfg+i*HH,lnfb+i*HH, lnsg+i*HH,lnsb+i*HH,
            tw+i*SS*SS, tb+i*SS, fw+i*HH*HH, fb+i*HH, sw+i*HH*HH);
        k_pack_xp<<<gpack,256,0,stream>>>(xpb, xpg);
        k_bmm_mfma<<<gbmm,256,0,stream>>>(combh, xpg, sb+i*HH, h);
    }
    k_head<<<BB*NN,256,0,stream>>>(h, xfut, futw, futb, hw, hb, out);
}

// Round 3
// 963.148 us; speedup vs baseline: 4.4138x; 2.2086x over previous
//
#include <hip/hip_runtime.h>
#include <hip/hip_bf16.h>
#include <math.h>

#define BB 4
#define NN 1437
#define SS 56
#define PP 28
#define FIN 10
#define FFUT 6
#define HH 64
#define NBLK 2
#define TOPK 5
#define DD (SS*HH)     /* 3584 */
#define FD (PP*HH)     /* 1792 */
#define TOT (DD+FD)    /* 5376 */
#define MP 1536        /* padded M (12*128) */
#define KP 1472        /* padded K (46*32)  */
#define NT (KP/32)     /* 46 K-steps */
#define WIMG_SZ 16384  /* shorts per mixer-block weight image */

typedef __attribute__((ext_vector_type(8))) __bf16 bf16x8;
typedef __attribute__((ext_vector_type(4))) float  f32x4;

__device__ __forceinline__ float gelu_exact(float x){
    return 0.5f*x*(1.0f+erff(x*0.70710678118654752440f));
}
__device__ __forceinline__ float wave_sum64(float v){
    #pragma unroll
    for (int o=1;o<64;o<<=1) v += __shfl_xor(v,o,64);
    return v;
}
__device__ __forceinline__ void async_load16(const void* g, void* l){
    __builtin_amdgcn_global_load_lds(
        (const __attribute__((address_space(1))) void*)g,
        (__attribute__((address_space(3))) void*)l, 16, 0, 0);
}
__device__ __forceinline__ unsigned short f2bf(float x){
    unsigned int u = __float_as_uint(x);
    unsigned int r = (u + 0x7fffu + ((u>>16)&1u)) >> 16;
    return (unsigned short)r;
}

// ---------------- emb norm ----------------
__global__ __launch_bounds__(64) void k_embnorm(const float* __restrict__ emb,
                                                float* __restrict__ out){
    int n = blockIdx.x; int l = threadIdx.x;
    float v = emb[(size_t)n*HH+l];
    float ss = wave_sum64(v*v);
    float nrm = fmaxf(sqrtf(ss), 1e-12f);
    out[(size_t)n*HH+l] = v/nrm;
}

// ------- front: h = LN(x@fp_w^T+fp_b)+embn ; ctx = recency ctx -------
__global__ __launch_bounds__(256) void k_front(
    const float* __restrict__ x, const float* __restrict__ fpw, const float* __restrict__ fpb,
    const float* __restrict__ lng, const float* __restrict__ lnb,
    const float* __restrict__ embn, float* __restrict__ h, float* __restrict__ ctx)
{
    int bn = blockIdx.x; int n = bn % NN;
    int tid=threadIdx.x; int lane=tid&63; int wv=tid>>6;
    __shared__ float xin[SS*FIN];
    __shared__ float wlds[HH*FIN];
    __shared__ float rw[SS];
    __shared__ float rsum;
    __shared__ float red[4][HH];
    for (int i=tid;i<SS*FIN;i+=256) xin[i]=x[(size_t)bn*SS*FIN+i];
    for (int i=tid;i<HH*FIN;i+=256) wlds[i]=fpw[i];
    if (tid<SS) rw[tid]=expf(-(float)(SS-tid)/14.0f);
    __syncthreads();
    if (tid==0){ float s=0.f; for(int i=0;i<SS;++i) s+=rw[i]; rsum=s; }
    __syncthreads();
    float inv_rs = 1.0f/rsum;
    float gg=lng[lane], bv=lnb[lane], el=embn[(size_t)n*HH+lane], fb0=fpb[lane];
    float cacc=0.f;
    for (int s=wv;s<SS;s+=4){
        float v=fb0;
        #pragma unroll
        for (int c=0;c<FIN;++c) v += xin[s*FIN+c]*wlds[lane*FIN+c];
        float m = wave_sum64(v)*(1.f/HH);
        float d = v-m;
        float va = wave_sum64(d*d)*(1.f/HH);
        float hn = d*rsqrtf(va+1e-5f)*gg + bv + el;
        h[((size_t)bn*SS+s)*HH+lane]=hn;
        cacc += hn * rw[s]*inv_rs;
    }
    red[wv][lane]=cacc;
    __syncthreads();
    if (wv==0) ctx[(size_t)bn*HH+lane]=red[0][lane]+red[1][lane]+red[2][lane]+red[3][lane];
}

// ---------------- Q/K projections ----------------
__global__ __launch_bounds__(64) void k_qk(
    const float* __restrict__ ctx, const float* __restrict__ qw, const float* __restrict__ qb,
    const float* __restrict__ kw, const float* __restrict__ kb,
    float* __restrict__ Q, float* __restrict__ K)
{
    __shared__ float wq[HH*65];
    __shared__ float wk2[HH*65];
    int lane=threadIdx.x; int bn=blockIdx.x;
    for (int i=lane;i<HH*HH;i+=64){ int hh=i>>6, kk=i&63; wq[kk*65+hh]=qw[i]; wk2[kk*65+hh]=kw[i]; }
    __syncthreads();
    const float* c = ctx + (size_t)bn*HH;
    float q=qb[lane], k=kb[lane];
    for (int kk=0;kk<HH;++kk){ float cv=c[kk]; q+=cv*wq[kk*65+lane]; k+=cv*wk2[kk*65+lane]; }
    Q[(size_t)bn*HH+lane]=q; K[(size_t)bn*HH+lane]=k;
}

// ------- comb row → bf16 padded A matrix [MP][KP] -------
__global__ __launch_bounds__(256) void k_comb(
    const float* __restrict__ Q, const float* __restrict__ K,
    const float* __restrict__ adj, const float* __restrict__ galpha,
    __hip_bfloat16* __restrict__ combh)
{
    int m=blockIdx.x, b=blockIdx.y, tid=threadIdx.x;
    __shared__ __align__(16) float qv[HH];
    __shared__ float row[NN];
    __shared__ float redv[256];
    __shared__ int   redi[256];
    __shared__ float selv[TOPK];
    __shared__ int   seli[TOPK];
    __shared__ float sden;
    if (tid<HH) qv[tid]=Q[((size_t)b*NN+m)*HH+tid];
    __syncthreads();
    for (int n=tid;n<NN;n+=256){
        const float4* kr=reinterpret_cast<const float4*>(K+((size_t)b*NN+n)*HH);
        const float4* q4=reinterpret_cast<const float4*>(qv);
        float d=0.f;
        #pragma unroll
        for (int t=0;t<16;++t){
            float4 kv=kr[t], qq=q4[t];
            d += kv.x*qq.x+kv.y*qq.y+kv.z*qq.z+kv.w*qq.w;
        }
        d*=0.125f;
        d=fminf(fmaxf(d,-10.f),10.f);
        d=fmaxf(d,0.f);
        row[n]=d;
    }
    __syncthreads();
    for (int it=0;it<TOPK;++it){
        float bv=-1e30f; int bi=NN;
        for (int n=tid;n<NN;n+=256){
            float v=row[n];
            if (v>bv||(v==bv&&n<bi)){bv=v;bi=n;}
        }
        redv[tid]=bv; redi[tid]=bi;
        __syncthreads();
        for (int off=128;off>0;off>>=1){
            if (tid<off){
                float v2=redv[tid+off]; int i2=redi[tid+off];
                if (v2>redv[tid]||(v2==redv[tid]&&i2<redi[tid])){redv[tid]=v2;redi[tid]=i2;}
            }
            __syncthreads();
        }
        if (tid==0){ selv[it]=redv[0]; seli[it]=redi[0]; row[redi[0]]=-1e30f; }
        __syncthreads();
    }
    if (tid==0){
        float mx=selv[0], s=0.f;
        for (int j=0;j<TOPK;++j) s+=expf(selv[j]-mx);
        sden=s;
    }
    __syncthreads();
    float alpha=1.f/(1.f+expf(-galpha[0]));
    float mx=selv[0], sd=sden;
    float part=0.f;
    for (int n=tid;n<NN;n+=256){
        float v=alpha*adj[(size_t)m*NN+n];
        #pragma unroll
        for (int j=0;j<TOPK;++j) if (n==seli[j]) v += (1.f-alpha)*expf(selv[j]-mx)/sd;
        row[n]=v;
        part+=fabsf(v);
    }
    redv[tid]=part;
    __syncthreads();
    for (int off=128;off>0;off>>=1){
        if (tid<off) redv[tid]+=redv[tid+off];
        __syncthreads();
    }
    float inv=1.f/fmaxf(redv[0],1e-12f);
    __hip_bfloat16* dst = combh + ((size_t)b*MP+m)*KP;
    for (int n=tid;n<KP;n+=256){
        float v = (n<NN) ? row[n]*inv : 0.f;
        dst[n]=__float2bfloat16(v);
    }
}

// ---- prep: build per-mixer-block bf16 weight images ----
// layout (shorts, per block i):
//   [0..4096)     Mw  (conv matrix)  row-major [64][64], XOR-swizzled
//   [4096..8192)  twp (temporal)     row-major [64][64], XOR-swizzled
//   [8192..12288) fwp (feature)      K-packed [fp/8][f][8]
//   [12288..16384)swp (spatial)      K-packed [fp/8][f][8]
__global__ __launch_bounds__(256) void k_prepw(
    const float* __restrict__ wk, const float* __restrict__ mk,
    const float* __restrict__ tw, const float* __restrict__ fw,
    const float* __restrict__ sw, unsigned short* __restrict__ wimg)
{
    int i = blockIdx.x; int tid = threadIdx.x;
    const float* wki = wk + i*7;
    const float* mki = mk + i*28;
    const float* twi = tw + i*SS*SS;
    const float* fwi = fw + i*HH*HH;
    const float* swi = sw + i*HH*HH;
    unsigned short* o = wimg + (size_t)i*WIMG_SZ;
    for (int e=tid; e<4096; e+=256){
        int r = e>>6, k = e&63;
        int swz = ((k*2) ^ ((r&7)<<4)) >> 1;   // short index within row
        float mv = 0.f;
        if (r<SS && k<SS){
            int a = k-r+3;  if (a>=0 && a<7)  mv += wki[a];
            int b2= k-r+13; if (b2>=0 && b2<28) mv += mki[b2];
        }
        o[r*64 + swz] = f2bf(mv);
        float tv = (r<SS && k<SS) ? twi[r*SS+k] : 0.f;
        o[4096 + r*64 + swz] = f2bf(tv);
        int pk = (k>>3)*512 + r*8 + (k&7);
        o[8192  + pk] = f2bf(fwi[r*HH+k]);
        o[12288 + pk] = f2bf(swi[r*HH+k]);
    }
}

// ---------------- MFMA mixer block ----------------
// 4 waves; wave w owns output rows [16w,16w+16). Registers hold the tile:
// element (q,tj) of thread = (s=16w+4*(lane>>4)+q, f=16tj+(lane&15))  [MFMA C/D layout]
__global__ __launch_bounds__(256) void k_mixer2(
    float* __restrict__ h, __hip_bfloat16* __restrict__ xpb,
    const unsigned short* __restrict__ wimg,
    const float* __restrict__ lncg, const float* __restrict__ lncb,
    const float* __restrict__ lntg, const float* __restrict__ lntb,
    const float* __restrict__ lnfg, const float* __restrict__ lnfb,
    const float* __restrict__ lnsg, const float* __restrict__ lnsb,
    const float* __restrict__ tb, const float* __restrict__ fb)
{
    int bn=blockIdx.x, tid=threadIdx.x, lane=tid&63, w=tid>>6;
    int g=lane>>4, c=lane&15;
    __shared__ unsigned short wbuf[4][4096];
    __shared__ unsigned short xs[4096];
    __shared__ float prm[640];

    const char* wsrc=(const char*)wimg;
    char* wdst=(char*)&wbuf[0][0];
    #pragma unroll
    for (int i=0;i<8;++i)
        async_load16(wsrc+((size_t)(i*256+tid))*16, wdst+(i*256+w*64)*16);
    if (tid<64){
        prm[tid]      =lncg[tid]; prm[64+tid] =lncb[tid];
        prm[128+tid]  =lntg[tid]; prm[192+tid]=lntb[tid];
        prm[256+tid]  =lnfg[tid]; prm[320+tid]=lnfb[tid];
        prm[384+tid]  =lnsg[tid]; prm[448+tid]=lnsb[tid];
        prm[512+tid]  =(tid<SS)?tb[tid]:0.f;
        prm[576+tid]  =fb[tid];
    }
    float xl[4][4];
    float* hb = h + (size_t)bn*DD;
    int srow = 16*w + 4*g;
    #pragma unroll
    for (int q=0;q<4;++q){
        int s=srow+q;
        #pragma unroll
        for (int tj=0;tj<4;++tj)
            xl[q][tj] = (s<SS) ? hb[s*HH + tj*16 + c] : 0.f;
    }
    __syncthreads();   // drains the global_load_lds

    float xn[4][4];
    f32x4 acc[4];

#define LNSTAGE(GOFF,BOFF) do{ \
    _Pragma("unroll") \
    for (int q=0;q<4;++q){ \
        float sv = xl[q][0]+xl[q][1]+xl[q][2]+xl[q][3]; \
        float s2 = xl[q][0]*xl[q][0]+xl[q][1]*xl[q][1]+xl[q][2]*xl[q][2]+xl[q][3]*xl[q][3]; \
        _Pragma("unroll") \
        for (int m2=1;m2<16;m2<<=1){ sv += __shfl_xor(sv,m2,64); s2 += __shfl_xor(s2,m2,64); } \
        float mn = sv*(1.f/64.f); \
        float var = s2*(1.f/64.f)-mn*mn; \
        float rstd = rsqrtf(var+1e-5f); \
        bool ok = (srow+q)<SS; \
        _Pragma("unroll") \
        for (int tj=0;tj<4;++tj){ \
            float v=(xl[q][tj]-mn)*rstd*prm[(GOFF)+tj*16+c]+prm[(BOFF)+tj*16+c]; \
            xn[q][tj]= ok ? v : 0.f; \
        } \
    } }while(0)

#define WRITE_XNP() do{ \
    _Pragma("unroll") \
    for (int qp=0;qp<2;++qp){ \
        int s0=srow+2*qp; \
        _Pragma("unroll") \
        for (int tj=0;tj<4;++tj){ \
            unsigned int pv=(unsigned int)f2bf(xn[2*qp][tj])|((unsigned int)f2bf(xn[2*qp+1][tj])<<16); \
            *(unsigned int*)((char*)xs + ((s0>>3)*1024 + (tj*16+c)*16 + (s0&7)*2)) = pv; \
        } \
    } }while(0)

#define WRITE_XNR() do{ \
    _Pragma("unroll") \
    for (int q=0;q<4;++q){ int s=srow+q; \
        _Pragma("unroll") \
        for (int tj=0;tj<4;++tj){ \
            *(unsigned short*)((char*)xs + s*128 + (((tj*16+c)*2) ^ ((s&7)<<4))) = f2bf(xn[q][tj]); \
        } \
    } }while(0)

#define MM(APTR,BPTR) do{ \
    _Pragma("unroll") \
    for (int tj=0;tj<4;++tj) acc[tj]=(f32x4){0.f,0.f,0.f,0.f}; \
    _Pragma("unroll") \
    for (int kc=0;kc<2;++kc){ \
        int arow=16*w+c; \
        bf16x8 af=*(const bf16x8*)((const char*)(APTR)+arow*128+((kc*64+g*16)^((arow&7)<<4))); \
        _Pragma("unroll") \
        for (int tj=0;tj<4;++tj){ \
            bf16x8 bf2=*(const bf16x8*)((const char*)(BPTR)+(kc*4+g)*1024+(tj*16+c)*16); \
            acc[tj]=__builtin_amdgcn_mfma_f32_16x16x32_bf16(af,bf2,acc[tj],0,0,0); \
        } \
    } }while(0)

    // ---- conv (as banded matmul) ----
    LNSTAGE(0,64); WRITE_XNP();
    __syncthreads();
    MM(&wbuf[0][0], xs);
    #pragma unroll
    for (int q=0;q<4;++q)
        #pragma unroll
        for (int tj=0;tj<4;++tj) xl[q][tj]+=acc[tj][q];
    __syncthreads();
    // ---- temporal MLP ----
    LNSTAGE(128,192); WRITE_XNP();
    __syncthreads();
    MM(&wbuf[1][0], xs);
    #pragma unroll
    for (int q=0;q<4;++q){
        float tbv=prm[512+srow+q];
        #pragma unroll
        for (int tj=0;tj<4;++tj) xl[q][tj]+=gelu_exact(acc[tj][q]+tbv);
    }
    __syncthreads();
    // ---- feature MLP ----
    LNSTAGE(256,320); WRITE_XNR();
    __syncthreads();
    MM(xs, &wbuf[2][0]);
    #pragma unroll
    for (int q=0;q<4;++q)
        #pragma unroll
        for (int tj=0;tj<4;++tj) xl[q][tj]+=gelu_exact(acc[tj][q]+prm[576+tj*16+c]);
    __syncthreads();
    // ---- spatial projection ----
    LNSTAGE(384,448); WRITE_XNR();
    __syncthreads();
    MM(xs, &wbuf[3][0]);
    __hip_bfloat16* xpo = xpb + (size_t)bn*DD;
    #pragma unroll
    for (int q=0;q<4;++q){
        int s=srow+q;
        if (s<SS){
            #pragma unroll
            for (int tj=0;tj<4;++tj){
                int d=s*HH+tj*16+c;
                hb[d]=xl[q][tj];
                xpo[d]=__float2bfloat16(acc[tj][q]);
            }
        }
    }
#undef LNSTAGE
#undef WRITE_XNP
#undef WRITE_XNR
#undef MM
}

// ---- pack xp bf16 [N][D] -> MFMA-ready [KP/8][D][8] with K zero-pad ----
__global__ __launch_bounds__(256) void k_pack_xp(
    const __hip_bfloat16* __restrict__ xpb, __hip_bfloat16* __restrict__ xpg)
{
    int d = blockIdx.x*256 + threadIdx.x;
    int kc = blockIdx.y; int b = blockIdx.z;
    union { __hip_bfloat16 hv[8]; float4 f4; } u;
    #pragma unroll
    for (int j=0;j<8;++j){
        int k = kc*8+j;
        u.hv[j] = (k<NN) ? xpb[((size_t)b*NN+k)*DD + d] : __float2bfloat16(0.f);
    }
    *reinterpret_cast<float4*>(&xpg[(((size_t)b*(KP/8)+kc)*DD + d)*8]) = u.f4;
}

// ---------------- spatial bmm via MFMA: h[b] += comb[b] @ xp[b] + sb ----------------
__global__ __launch_bounds__(256) void k_bmm_mfma(
    const __hip_bfloat16* __restrict__ combh,  // [B][MP][KP] row-major, zero-padded
    const __hip_bfloat16* __restrict__ xpg,    // [B][KP/8][D][8] packed, zero-padded
    const float* __restrict__ sb,
    float* __restrict__ h)                     // [B][N][D] f32, accumulated
{
    int bm=blockIdx.x, bd=blockIdx.y, b=blockIdx.z;
    int tid=threadIdx.x; int lane=tid&63; int wv=tid>>6;
    int m0=bm*128, d0=bd*128;
    __shared__ short As[2][4096];
    __shared__ short Bs[2][4096];

    const char* cb = (const char*)(combh + (size_t)b*MP*KP);
    const char* xb = (const char*)(xpg   + (size_t)b*(KP/8)*(size_t)DD*8);

    int ia0 = wv*2, ia1 = wv*2+1;
    int g0 = ia0*64 + lane, g1 = ia1*64 + lane;
    const char* srcA0 = cb + ((size_t)(m0 + (g0&127))*KP + (g0>>7)*8)*2;
    const char* srcA1 = cb + ((size_t)(m0 + (g1&127))*KP + (g1>>7)*8)*2;
    const char* srcB0 = xb + ((size_t)(g0>>7)*DD + d0 + (g0&127))*16;
    const char* srcB1 = xb + ((size_t)(g1>>7)*DD + d0 + (g1&127))*16;
    const size_t BSTEP = (size_t)4*DD*16;

    int wr=wv>>1, wc=wv&1;
    int aoff[4], boff[4];
    #pragma unroll
    for (int i=0;i<4;++i) aoff[i] = ((lane>>4)*128 + wr*64 + i*16 + (lane&15))*8;
    #pragma unroll
    for (int j=0;j<4;++j) boff[j] = ((lane>>4)*128 + wc*64 + j*16 + (lane&15))*8;

    f32x4 acc[4][4];
    #pragma unroll
    for (int i=0;i<4;++i)
        #pragma unroll
        for (int j=0;j<4;++j) acc[i][j]=(f32x4){0.f,0.f,0.f,0.f};

#define STAGE(CUR) do { \
    async_load16(srcA0, &As[CUR][ia0*512]); \
    async_load16(srcA1, &As[CUR][ia1*512]); \
    async_load16(srcB0, &Bs[CUR][ia0*512]); \
    async_load16(srcB1, &Bs[CUR][ia1*512]); \
    srcA0+=64; srcA1+=64; srcB0+=BSTEP; srcB1+=BSTEP; } while(0)

    STAGE(0);
    asm volatile("s_waitcnt vmcnt(0)");
    __syncthreads();
    int cur=0;
    for (int t=0;t<NT;++t){
        if (t+1<NT) STAGE(cur^1);
        const short* Ab=As[cur]; const short* Bb=Bs[cur];
        bf16x8 af[4], bfv[4];
        #pragma unroll
        for (int i=0;i<4;++i) af[i]=*reinterpret_cast<const bf16x8*>(Ab + aoff[i]);
        #pragma unroll
        for (int j=0;j<4;++j) bfv[j]=*reinterpret_cast<const bf16x8*>(Bb + boff[j]);
        #pragma unroll
        for (int i=0;i<4;++i)
            #pragma unroll
            for (int j=0;j<4;++j)
                acc[i][j]=__builtin_amdgcn_mfma_f32_16x16x32_bf16(af[i],bfv[j],acc[i][j],0,0,0);
        __syncthreads();
        cur^=1;
    }
#undef STAGE

    int row0 = m0 + wr*64 + (lane>>4)*4;
    int colb = d0 + wc*64 + (lane&15);
    #pragma unroll
    for (int i=0;i<4;++i){
        #pragma unroll
        for (int q=0;q<4;++q){
            int m = row0 + i*16 + q;
            if (m < NN){
                size_t rb = ((size_t)b*NN+m)*DD;
                #pragma unroll
                for (int j=0;j<4;++j){
                    int d = colb + j*16;
                    h[rb+d] += acc[i][j][q] + sb[(lane&15)+j*16];
                }
            }
        }
    }
}

// ---------------- head ----------------
__global__ __launch_bounds__(256) void k_head(
    const float* __restrict__ h, const float* __restrict__ xf,
    const float* __restrict__ fw, const float* __restrict__ fbias,
    const float* __restrict__ hw, const float* __restrict__ hb,
    float* __restrict__ out)
{
    int bn=blockIdx.x; int tid=threadIdx.x; int lane=tid&63; int wv=tid>>6;
    __shared__ float fut[FD];
    __shared__ float fwl[HH*FFUT];
    __shared__ float fbl[HH];
    __shared__ float xfl[PP*FFUT];
    __shared__ float red[4][PP];
    for (int i=tid;i<HH*FFUT;i+=256) fwl[i]=fw[i];
    if (tid<HH) fbl[tid]=fbias[tid];
    for (int i=tid;i<PP*FFUT;i+=256) xfl[i]=xf[(size_t)bn*PP*FFUT+i];
    __syncthreads();
    for (int q=tid;q<FD;q+=256){
        int pp=q>>6, hh2=q&63;
        float v=fbl[hh2];
        #pragma unroll
        for (int c=0;c<FFUT;++c) v += xfl[pp*FFUT+c]*fwl[hh2*FFUT+c];
        fut[q]=v;
    }
    __syncthreads();
    float acc[PP];
    #pragma unroll
    for (int p=0;p<PP;++p) acc[p]=0.f;
    const float* hrow = h + (size_t)bn*DD;
    for (int d=tid; d<TOT; d+=256){
        float v = (d<DD)?hrow[d]:fut[d-DD];
        #pragma unroll
        for (int p=0;p<PP;++p) acc[p] += v*hw[(size_t)p*TOT+d];
    }
    #pragma unroll
    for (int p=0;p<PP;++p){
        float a=wave_sum64(acc[p]);
        if (lane==0) red[wv][p]=a;
    }
    __syncthreads();
    if (tid<PP) out[(size_t)bn*PP+tid] = red[0][tid]+red[1][tid]+red[2][tid]+red[3][tid] + hb[tid];
}

extern "C" void kernel_launch(void* const* d_in, const int* in_sizes, int n_in,
                              void* d_out, int out_size, void* d_ws, size_t ws_size,
                              hipStream_t stream)
{
    const float* x      = (const float*)d_in[0];
    const float* xfut   = (const float*)d_in[1];
    const float* adj    = (const float*)d_in[2];
    const float* fp_w   = (const float*)d_in[3];
    const float* fp_b   = (const float*)d_in[4];
    const float* inlng  = (const float*)d_in[5];
    const float* inlnb  = (const float*)d_in[6];
    const float* q_w    = (const float*)d_in[7];
    const float* q_b    = (const float*)d_in[8];
    const float* k_w    = (const float*)d_in[9];
    const float* k_b    = (const float*)d_in[10];
    const float* nemb   = (const float*)d_in[11];
    const float* galpha = (const float*)d_in[12];
    const float* wk     = (const float*)d_in[13];
    const float* mk     = (const float*)d_in[14];
    const float* lncg   = (const float*)d_in[15];
    const float* lncb   = (const float*)d_in[16];
    const float* lntg   = (const float*)d_in[17];
    const float* lntb   = (const float*)d_in[18];
    const float* lnfg   = (const float*)d_in[19];
    const float* lnfb   = (const float*)d_in[20];
    const float* lnsg   = (const float*)d_in[21];
    const float* lnsb   = (const float*)d_in[22];
    const float* tw     = (const float*)d_in[23];
    const float* tb     = (const float*)d_in[24];
    const float* fw     = (const float*)d_in[25];
    const float* fb     = (const float*)d_in[26];
    const float* sw     = (const float*)d_in[27];
    const float* sb     = (const float*)d_in[28];
    const float* futw   = (const float*)d_in[29];
    const float* futb   = (const float*)d_in[30];
    const float* hw     = (const float*)d_in[31];
    const float* hb     = (const float*)d_in[32];
    (void)in_sizes; (void)n_in; (void)out_size; (void)ws_size;
    float* out = (float*)d_out;
    float* ws = (float*)d_ws;
    const size_t HSZ = (size_t)BB*NN*SS*HH;     // 20,600,832

    float* h    = ws;
    float* embn = h + HSZ;
    float* ctx  = embn + (size_t)NN*HH;
    float* Q    = ctx + (size_t)BB*NN*HH;
    float* K    = Q + (size_t)BB*NN*HH;
    __hip_bfloat16* xpb   = (__hip_bfloat16*)(K + (size_t)BB*NN*HH);
    __hip_bfloat16* combh = xpb + HSZ;
    __hip_bfloat16* xpg   = combh + (size_t)BB*MP*KP;
    unsigned short* wimg  = (unsigned short*)(xpg + (size_t)BB*(KP/8)*(size_t)DD*8);

    k_prepw<<<NBLK,256,0,stream>>>(wk, mk, tw, fw, sw, wimg);
    k_embnorm<<<NN,64,0,stream>>>(nemb, embn);
    k_front<<<BB*NN,256,0,stream>>>(x, fp_w, fp_b, inlng, inlnb, embn, h, ctx);
    k_qk<<<BB*NN,64,0,stream>>>(ctx, q_w,q_b,k_w,k_b,Q,K);
    hipMemsetAsync(combh, 0, (size_t)BB*MP*KP*sizeof(__hip_bfloat16), stream);
    dim3 gcomb(NN,BB);
    k_comb<<<gcomb,256,0,stream>>>(Q,K,adj,galpha,combh);
    dim3 gpack(DD/256, KP/8, BB);
    dim3 gbmm(MP/128, DD/128, BB);
    for (int i=0;i<NBLK;++i){
        k_mixer2<<<BB*NN,256,0,stream>>>(h, xpb, wimg + (size_t)i*WIMG_SZ,
            lncg+i*HH,lncb+i*HH, lntg+i*HH,lntb+i*HH, lnfg+i*HH,lnfb+i*HH, lnsg+i*HH,lnsb+i*HH,
            tb+i*SS, fb+i*HH);
        k_pack_xp<<<gpack,256,0,stream>>>(xpb, xpg);
        k_bmm_mfma<<<gbmm,256,0,stream>>>(combh, xpg, sb+i*HH, h);
    }
    k_head<<<BB*NN,256,0,stream>>>(h, xfut, futw, futb, hw, hb, out);
}

// Round 4
// 775.787 us; speedup vs baseline: 5.4798x; 1.2415x over previous
//
#include <hip/hip_runtime.h>
#include <hip/hip_bf16.h>
#include <math.h>

#define BB 4
#define NN 1437
#define SS 56
#define PP 28
#define FIN 10
#define FFUT 6
#define HH 64
#define NBLK 2
#define TOPK 5
#define DD (SS*HH)     /* 3584 */
#define FD (PP*HH)     /* 1792 */
#define TOT (DD+FD)    /* 5376 */
#define MP 1536        /* padded M (12*128) */
#define KP 1472        /* padded K (46*32)  */
#define NT (KP/32)     /* 46 K-steps */
#define SP 1536        /* scores stride */
#define WIMG_SZ 16384  /* shorts per mixer-block weight image */

typedef __attribute__((ext_vector_type(8))) __bf16 bf16x8;
typedef __attribute__((ext_vector_type(4))) float  f32x4;

__device__ __forceinline__ float gelu_exact(float x){
    return 0.5f*x*(1.0f+erff(x*0.70710678118654752440f));
}
__device__ __forceinline__ float wave_sum64(float v){
    #pragma unroll
    for (int o=1;o<64;o<<=1) v += __shfl_xor(v,o,64);
    return v;
}
__device__ __forceinline__ void async_load16(const void* g, void* l){
    __builtin_amdgcn_global_load_lds(
        (const __attribute__((address_space(1))) void*)g,
        (__attribute__((address_space(3))) void*)l, 16, 0, 0);
}
__device__ __forceinline__ unsigned short f2bf(float x){
    unsigned int u = __float_as_uint(x);
    unsigned int r = (u + 0x7fffu + ((u>>16)&1u)) >> 16;
    return (unsigned short)r;
}
__device__ __forceinline__ unsigned long long umax64(unsigned long long a, unsigned long long b){return a>b?a:b;}
__device__ __forceinline__ unsigned long long umin64(unsigned long long a, unsigned long long b){return a<b?a:b;}

// ---------------- emb norm ----------------
__global__ __launch_bounds__(64) void k_embnorm(const float* __restrict__ emb,
                                                float* __restrict__ out){
    int n = blockIdx.x; int l = threadIdx.x;
    float v = emb[(size_t)n*HH+l];
    float ss = wave_sum64(v*v);
    float nrm = fmaxf(sqrtf(ss), 1e-12f);
    out[(size_t)n*HH+l] = v/nrm;
}

// ------- front: h = LN(x@fp_w^T+fp_b)+embn ; ctx = recency ctx -------
__global__ __launch_bounds__(256) void k_front(
    const float* __restrict__ x, const float* __restrict__ fpw, const float* __restrict__ fpb,
    const float* __restrict__ lng, const float* __restrict__ lnb,
    const float* __restrict__ embn, float* __restrict__ h, float* __restrict__ ctx)
{
    int bn = blockIdx.x; int n = bn % NN;
    int tid=threadIdx.x; int lane=tid&63; int wv=tid>>6;
    __shared__ float xin[SS*FIN];
    __shared__ float wlds[HH*FIN];
    __shared__ float rw[SS];
    __shared__ float rsum;
    __shared__ float red[4][HH];
    for (int i=tid;i<SS*FIN;i+=256) xin[i]=x[(size_t)bn*SS*FIN+i];
    for (int i=tid;i<HH*FIN;i+=256) wlds[i]=fpw[i];
    if (tid<SS) rw[tid]=expf(-(float)(SS-tid)/14.0f);
    __syncthreads();
    if (tid==0){ float s=0.f; for(int i=0;i<SS;++i) s+=rw[i]; rsum=s; }
    __syncthreads();
    float inv_rs = 1.0f/rsum;
    float gg=lng[lane], bv=lnb[lane], el=embn[(size_t)n*HH+lane], fb0=fpb[lane];
    float cacc=0.f;
    for (int s=wv;s<SS;s+=4){
        float v=fb0;
        #pragma unroll
        for (int c=0;c<FIN;++c) v += xin[s*FIN+c]*wlds[lane*FIN+c];
        float m = wave_sum64(v)*(1.f/HH);
        float d = v-m;
        float va = wave_sum64(d*d)*(1.f/HH);
        float hn = d*rsqrtf(va+1e-5f)*gg + bv + el;
        h[((size_t)bn*SS+s)*HH+lane]=hn;
        cacc += hn * rw[s]*inv_rs;
    }
    red[wv][lane]=cacc;
    __syncthreads();
    if (wv==0) ctx[(size_t)bn*HH+lane]=red[0][lane]+red[1][lane]+red[2][lane]+red[3][lane];
}

// ---------------- Q/K projections -> K-packed bf16 [b][8][MP][8] ----------------
__global__ __launch_bounds__(64) void k_qk(
    const float* __restrict__ ctx, const float* __restrict__ qw, const float* __restrict__ qb,
    const float* __restrict__ kw, const float* __restrict__ kb,
    unsigned short* __restrict__ qpack, unsigned short* __restrict__ kpack)
{
    __shared__ float wq[HH*65];
    __shared__ float wk2[HH*65];
    int lane=threadIdx.x; int bn=blockIdx.x;
    for (int i=lane;i<HH*HH;i+=64){ int hh=i>>6, kk=i&63; wq[kk*65+hh]=qw[i]; wk2[kk*65+hh]=kw[i]; }
    __syncthreads();
    const float* c = ctx + (size_t)bn*HH;
    float q=qb[lane], k=kb[lane];
    for (int kk=0;kk<HH;++kk){ float cv=c[kk]; q+=cv*wq[kk*65+lane]; k+=cv*wk2[kk*65+lane]; }
    int b = bn/NN, m = bn%NN;
    size_t off = (size_t)b*8*MP*8 + (size_t)(lane>>3)*MP*8 + (size_t)m*8 + (lane&7);
    qpack[off]=f2bf(q); kpack[off]=f2bf(k);
}

// ---------------- QK^T via MFMA -> scores = relu(clip(QK^T/8)) f32 ----------------
__global__ __launch_bounds__(256) void k_qkt(
    const unsigned short* __restrict__ qp, const unsigned short* __restrict__ kp,
    float* __restrict__ scores)
{
    int bm=blockIdx.x, bnn=blockIdx.y, b=blockIdx.z;
    int tid=threadIdx.x, lane=tid&63, wv=tid>>6;
    int g=lane>>4, c15=lane&15;
    int m0=bm*128, n0=bnn*128;
    __shared__ unsigned short As[8192];  // [8][128][8]
    __shared__ unsigned short Bs[8192];
    const char* qbase = (const char*)(qp + (size_t)b*8*MP*8);
    const char* kbase = (const char*)(kp + (size_t)b*8*MP*8);
    #pragma unroll
    for (int i=0;i<4;++i){
        int idx=i*256+tid; int ch=idx>>7, r=idx&127;
        async_load16(qbase + ((size_t)(ch*MP + m0 + r))*16, (char*)As + idx*16);
        async_load16(kbase + ((size_t)(ch*MP + n0 + r))*16, (char*)Bs + idx*16);
    }
    asm volatile("s_waitcnt vmcnt(0)");
    __syncthreads();
    int wr=wv>>1, wc=wv&1;
    f32x4 acc[4][4];
    #pragma unroll
    for (int i=0;i<4;++i)
        #pragma unroll
        for (int j=0;j<4;++j) acc[i][j]=(f32x4){0.f,0.f,0.f,0.f};
    #pragma unroll
    for (int kc=0;kc<2;++kc){
        bf16x8 af[4], bfv[4];
        #pragma unroll
        for (int i=0;i<4;++i)
            af[i]=*(const bf16x8*)((const char*)As + ((4*kc+g)*128 + wr*64+i*16+c15)*16);
        #pragma unroll
        for (int j=0;j<4;++j)
            bfv[j]=*(const bf16x8*)((const char*)Bs + ((4*kc+g)*128 + wc*64+j*16+c15)*16);
        #pragma unroll
        for (int i=0;i<4;++i)
            #pragma unroll
            for (int j=0;j<4;++j)
                acc[i][j]=__builtin_amdgcn_mfma_f32_16x16x32_bf16(af[i],bfv[j],acc[i][j],0,0,0);
    }
    #pragma unroll
    for (int i=0;i<4;++i){
        #pragma unroll
        for (int q=0;q<4;++q){
            int m = m0 + wr*64 + i*16 + g*4 + q;
            float* sr = scores + ((size_t)b*SP + m)*SP + n0 + wc*64 + c15;
            #pragma unroll
            for (int j=0;j<4;++j){
                float v = acc[i][j][q]*0.125f;
                v = fminf(fmaxf(v,0.f),10.f);
                sr[j*16]=v;
            }
        }
    }
}

// ---- top-5 + softmax + blend + L1 normalize -> comb bf16 [b][MP][KP] ----
#define INS(x) do{ unsigned long long t_=(x); \
    unsigned long long n0_=umax64(u0,t_), t1_=umin64(u0,t_); \
    unsigned long long n1_=umax64(u1,t1_), t2_=umin64(u1,t1_); \
    unsigned long long n2_=umax64(u2,t2_), t3_=umin64(u2,t2_); \
    unsigned long long n3_=umax64(u3,t3_), t4_=umin64(u3,t3_); \
    unsigned long long n4_=umax64(u4,t4_); \
    u0=n0_;u1=n1_;u2=n2_;u3=n3_;u4=n4_; }while(0)

#define MERGE(b0,b1,b2,b3,b4) do{ \
    unsigned long long o0_=umax64(u0,(b0)); \
    unsigned long long o1_=umax64(umax64((b1),umin64(u0,(b0))),u1); \
    unsigned long long o2_=umax64(umax64((b2),umin64(u0,(b1))),umax64(umin64(u1,(b0)),u2)); \
    unsigned long long o3_=umax64(umax64((b3),umin64(u0,(b2))),umax64(umin64(u1,(b1)),umax64(umin64(u2,(b0)),u3))); \
    unsigned long long o4_=umax64(umax64((b4),umin64(u0,(b3))),umax64(umax64(umin64(u1,(b2)),umin64(u2,(b1))),umax64(umin64(u3,(b0)),u4))); \
    u0=o0_;u1=o1_;u2=o2_;u3=o3_;u4=o4_; }while(0)

__global__ __launch_bounds__(256) void k_topk(
    const float* __restrict__ scores, const float* __restrict__ adj,
    const float* __restrict__ galpha, __hip_bfloat16* __restrict__ combh)
{
    int m=blockIdx.x, b=blockIdx.y, tid=threadIdx.x, lane=tid&63, wv=tid>>6;
    __shared__ float row[KP];
    __shared__ unsigned long long wtop[4][8];
    __shared__ float redp[4];
    const float* srow = scores + ((size_t)b*SP + m)*SP;
    unsigned long long u0=0,u1=0,u2=0,u3=0,u4=0;
    for (int n=tid;n<NN;n+=256){
        float v=srow[n];
        unsigned long long key=((unsigned long long)__float_as_uint(v)<<32)|(unsigned long long)(0xFFFFFFFFu-(unsigned)n);
        INS(key);
    }
    #pragma unroll
    for (int off=1; off<64; off<<=1){
        unsigned long long b0=__shfl_xor(u0,off,64), b1=__shfl_xor(u1,off,64),
                           b2=__shfl_xor(u2,off,64), b3=__shfl_xor(u3,off,64),
                           b4=__shfl_xor(u4,off,64);
        MERGE(b0,b1,b2,b3,b4);
    }
    if (lane==0){ wtop[wv][0]=u0; wtop[wv][1]=u1; wtop[wv][2]=u2; wtop[wv][3]=u3; wtop[wv][4]=u4; }
    __syncthreads();
    u0=wtop[0][0]; u1=wtop[0][1]; u2=wtop[0][2]; u3=wtop[0][3]; u4=wtop[0][4];
    #pragma unroll
    for (int w2=1;w2<4;++w2)
        MERGE(wtop[w2][0],wtop[w2][1],wtop[w2][2],wtop[w2][3],wtop[w2][4]);

    float s0=__uint_as_float((unsigned)(u0>>32)), s1=__uint_as_float((unsigned)(u1>>32)),
          s2=__uint_as_float((unsigned)(u2>>32)), s3=__uint_as_float((unsigned)(u3>>32)),
          s4=__uint_as_float((unsigned)(u4>>32));
    int i0=(int)(0xFFFFFFFFu-(unsigned)u0), i1=(int)(0xFFFFFFFFu-(unsigned)u1),
        i2=(int)(0xFFFFFFFFu-(unsigned)u2), i3=(int)(0xFFFFFFFFu-(unsigned)u3),
        i4=(int)(0xFFFFFFFFu-(unsigned)u4);
    float e0=1.f, e1=expf(s1-s0), e2=expf(s2-s0), e3=expf(s3-s0), e4=expf(s4-s0);
    float den=e0+e1+e2+e3+e4;
    float alpha=1.f/(1.f+expf(-galpha[0]));
    float oma=(1.f-alpha)/den;
    float p0=oma*e0, p1=oma*e1, p2=oma*e2, p3=oma*e3, p4=oma*e4;

    const float* arow = adj + (size_t)m*NN;
    float part=0.f;
    for (int n=tid;n<NN;n+=256){
        float v=alpha*arow[n];
        v += (n==i0)?p0:0.f;
        v += (n==i1)?p1:0.f;
        v += (n==i2)?p2:0.f;
        v += (n==i3)?p3:0.f;
        v += (n==i4)?p4:0.f;
        row[n]=v;
        part+=fabsf(v);
    }
    part=wave_sum64(part);
    if (lane==0) redp[wv]=part;
    __syncthreads();
    float inv=1.f/fmaxf(redp[0]+redp[1]+redp[2]+redp[3],1e-12f);
    __hip_bfloat16* dst = combh + ((size_t)b*MP+m)*KP;
    for (int n=tid;n<KP;n+=256){
        float v = (n<NN) ? row[n]*inv : 0.f;
        dst[n]=__float2bfloat16(v);
    }
}
#undef INS
#undef MERGE

// ---- prep: build per-mixer-block bf16 weight images ----
__global__ __launch_bounds__(256) void k_prepw(
    const float* __restrict__ wk, const float* __restrict__ mk,
    const float* __restrict__ tw, const float* __restrict__ fw,
    const float* __restrict__ sw, unsigned short* __restrict__ wimg)
{
    int i = blockIdx.x; int tid = threadIdx.x;
    const float* wki = wk + i*7;
    const float* mki = mk + i*28;
    const float* twi = tw + i*SS*SS;
    const float* fwi = fw + i*HH*HH;
    const float* swi = sw + i*HH*HH;
    unsigned short* o = wimg + (size_t)i*WIMG_SZ;
    for (int e=tid; e<4096; e+=256){
        int r = e>>6, k = e&63;
        int swz = ((k*2) ^ ((r&7)<<4)) >> 1;
        float mv = 0.f;
        if (r<SS && k<SS){
            int a = k-r+3;  if (a>=0 && a<7)  mv += wki[a];
            int b2= k-r+13; if (b2>=0 && b2<28) mv += mki[b2];
        }
        o[r*64 + swz] = f2bf(mv);
        float tv = (r<SS && k<SS) ? twi[r*SS+k] : 0.f;
        o[4096 + r*64 + swz] = f2bf(tv);
        int pk = (k>>3)*512 + r*8 + (k&7);
        o[8192  + pk] = f2bf(fwi[r*HH+k]);
        o[12288 + pk] = f2bf(swi[r*HH+k]);
    }
}

// ---------------- MFMA mixer block ----------------
__global__ __launch_bounds__(256) void k_mixer2(
    float* __restrict__ h, __hip_bfloat16* __restrict__ xpb,
    const unsigned short* __restrict__ wimg,
    const float* __restrict__ lncg, const float* __restrict__ lncb,
    const float* __restrict__ lntg, const float* __restrict__ lntb,
    const float* __restrict__ lnfg, const float* __restrict__ lnfb,
    const float* __restrict__ lnsg, const float* __restrict__ lnsb,
    const float* __restrict__ tb, const float* __restrict__ fb)
{
    int bn=blockIdx.x, tid=threadIdx.x, lane=tid&63, w=tid>>6;
    int g=lane>>4, c=lane&15;
    __shared__ unsigned short wbuf[4][4096];
    __shared__ unsigned short xs[4096];
    __shared__ float prm[640];

    const char* wsrc=(const char*)wimg;
    char* wdst=(char*)&wbuf[0][0];
    #pragma unroll
    for (int i=0;i<8;++i)
        async_load16(wsrc+((size_t)(i*256+tid))*16, wdst+(i*256+w*64)*16);
    if (tid<64){
        prm[tid]      =lncg[tid]; prm[64+tid] =lncb[tid];
        prm[128+tid]  =lntg[tid]; prm[192+tid]=lntb[tid];
        prm[256+tid]  =lnfg[tid]; prm[320+tid]=lnfb[tid];
        prm[384+tid]  =lnsg[tid]; prm[448+tid]=lnsb[tid];
        prm[512+tid]  =(tid<SS)?tb[tid]:0.f;
        prm[576+tid]  =fb[tid];
    }
    float xl[4][4];
    float* hb = h + (size_t)bn*DD;
    int srow = 16*w + 4*g;
    #pragma unroll
    for (int q=0;q<4;++q){
        int s=srow+q;
        #pragma unroll
        for (int tj=0;tj<4;++tj)
            xl[q][tj] = (s<SS) ? hb[s*HH + tj*16 + c] : 0.f;
    }
    __syncthreads();

    float xn[4][4];
    f32x4 acc[4];

#define LNSTAGE(GOFF,BOFF) do{ \
    _Pragma("unroll") \
    for (int q=0;q<4;++q){ \
        float sv = xl[q][0]+xl[q][1]+xl[q][2]+xl[q][3]; \
        float s2 = xl[q][0]*xl[q][0]+xl[q][1]*xl[q][1]+xl[q][2]*xl[q][2]+xl[q][3]*xl[q][3]; \
        _Pragma("unroll") \
        for (int m2=1;m2<16;m2<<=1){ sv += __shfl_xor(sv,m2,64); s2 += __shfl_xor(s2,m2,64); } \
        float mn = sv*(1.f/64.f); \
        float var = s2*(1.f/64.f)-mn*mn; \
        float rstd = rsqrtf(var+1e-5f); \
        bool ok = (srow+q)<SS; \
        _Pragma("unroll") \
        for (int tj=0;tj<4;++tj){ \
            float v=(xl[q][tj]-mn)*rstd*prm[(GOFF)+tj*16+c]+prm[(BOFF)+tj*16+c]; \
            xn[q][tj]= ok ? v : 0.f; \
        } \
    } }while(0)

#define WRITE_XNP() do{ \
    _Pragma("unroll") \
    for (int qp=0;qp<2;++qp){ \
        int s0=srow+2*qp; \
        _Pragma("unroll") \
        for (int tj=0;tj<4;++tj){ \
            unsigned int pv=(unsigned int)f2bf(xn[2*qp][tj])|((unsigned int)f2bf(xn[2*qp+1][tj])<<16); \
            *(unsigned int*)((char*)xs + ((s0>>3)*1024 + (tj*16+c)*16 + (s0&7)*2)) = pv; \
        } \
    } }while(0)

#define WRITE_XNR() do{ \
    _Pragma("unroll") \
    for (int q=0;q<4;++q){ int s=srow+q; \
        _Pragma("unroll") \
        for (int tj=0;tj<4;++tj){ \
            *(unsigned short*)((char*)xs + s*128 + (((tj*16+c)*2) ^ ((s&7)<<4))) = f2bf(xn[q][tj]); \
        } \
    } }while(0)

#define MM(APTR,BPTR) do{ \
    _Pragma("unroll") \
    for (int tj=0;tj<4;++tj) acc[tj]=(f32x4){0.f,0.f,0.f,0.f}; \
    _Pragma("unroll") \
    for (int kc=0;kc<2;++kc){ \
        int arow=16*w+c; \
        bf16x8 af=*(const bf16x8*)((const char*)(APTR)+arow*128+((kc*64+g*16)^((arow&7)<<4))); \
        _Pragma("unroll") \
        for (int tj=0;tj<4;++tj){ \
            bf16x8 bf2=*(const bf16x8*)((const char*)(BPTR)+(kc*4+g)*1024+(tj*16+c)*16); \
            acc[tj]=__builtin_amdgcn_mfma_f32_16x16x32_bf16(af,bf2,acc[tj],0,0,0); \
        } \
    } }while(0)

    LNSTAGE(0,64); WRITE_XNP();
    __syncthreads();
    MM(&wbuf[0][0], xs);
    #pragma unroll
    for (int q=0;q<4;++q)
        #pragma unroll
        for (int tj=0;tj<4;++tj) xl[q][tj]+=acc[tj][q];
    __syncthreads();
    LNSTAGE(128,192); WRITE_XNP();
    __syncthreads();
    MM(&wbuf[1][0], xs);
    #pragma unroll
    for (int q=0;q<4;++q){
        float tbv=prm[512+srow+q];
        #pragma unroll
        for (int tj=0;tj<4;++tj) xl[q][tj]+=gelu_exact(acc[tj][q]+tbv);
    }
    __syncthreads();
    LNSTAGE(256,320); WRITE_XNR();
    __syncthreads();
    MM(xs, &wbuf[2][0]);
    #pragma unroll
    for (int q=0;q<4;++q)
        #pragma unroll
        for (int tj=0;tj<4;++tj) xl[q][tj]+=gelu_exact(acc[tj][q]+prm[576+tj*16+c]);
    __syncthreads();
    LNSTAGE(384,448); WRITE_XNR();
    __syncthreads();
    MM(xs, &wbuf[3][0]);
    __hip_bfloat16* xpo = xpb + (size_t)bn*DD;
    #pragma unroll
    for (int q=0;q<4;++q){
        int s=srow+q;
        if (s<SS){
            #pragma unroll
            for (int tj=0;tj<4;++tj){
                int d=s*HH+tj*16+c;
                hb[d]=xl[q][tj];
                xpo[d]=__float2bfloat16(acc[tj][q]);
            }
        }
    }
#undef LNSTAGE
#undef WRITE_XNP
#undef WRITE_XNR
#undef MM
}

// ---- pack xp bf16 [N][D] -> MFMA-ready [KP/8][D][8] with K zero-pad ----
__global__ __launch_bounds__(256) void k_pack_xp(
    const __hip_bfloat16* __restrict__ xpb, __hip_bfloat16* __restrict__ xpg)
{
    int d = blockIdx.x*256 + threadIdx.x;
    int kc = blockIdx.y; int b = blockIdx.z;
    union { __hip_bfloat16 hv[8]; float4 f4; } u;
    #pragma unroll
    for (int j=0;j<8;++j){
        int k = kc*8+j;
        u.hv[j] = (k<NN) ? xpb[((size_t)b*NN+k)*DD + d] : __float2bfloat16(0.f);
    }
    *reinterpret_cast<float4*>(&xpg[(((size_t)b*(KP/8)+kc)*DD + d)*8]) = u.f4;
}

// ---------------- spatial bmm via MFMA: h[b] += comb[b] @ xp[b] + sb ----------------
__global__ __launch_bounds__(256) void k_bmm_mfma(
    const __hip_bfloat16* __restrict__ combh,
    const __hip_bfloat16* __restrict__ xpg,
    const float* __restrict__ sb,
    float* __restrict__ h)
{
    int bm=blockIdx.x, bd=blockIdx.y, b=blockIdx.z;
    int tid=threadIdx.x; int lane=tid&63; int wv=tid>>6;
    int m0=bm*128, d0=bd*128;
    __shared__ short As[2][4096];
    __shared__ short Bs[2][4096];

    const char* cb = (const char*)(combh + (size_t)b*MP*KP);
    const char* xb = (const char*)(xpg   + (size_t)b*(KP/8)*(size_t)DD*8);

    int ia0 = wv*2, ia1 = wv*2+1;
    int g0 = ia0*64 + lane, g1 = ia1*64 + lane;
    const char* srcA0 = cb + ((size_t)(m0 + (g0&127))*KP + (g0>>7)*8)*2;
    const char* srcA1 = cb + ((size_t)(m0 + (g1&127))*KP + (g1>>7)*8)*2;
    const char* srcB0 = xb + ((size_t)(g0>>7)*DD + d0 + (g0&127))*16;
    const char* srcB1 = xb + ((size_t)(g1>>7)*DD + d0 + (g1&127))*16;
    const size_t BSTEP = (size_t)4*DD*16;

    int wr=wv>>1, wc=wv&1;
    int aoff[4], boff[4];
    #pragma unroll
    for (int i=0;i<4;++i) aoff[i] = ((lane>>4)*128 + wr*64 + i*16 + (lane&15))*8;
    #pragma unroll
    for (int j=0;j<4;++j) boff[j] = ((lane>>4)*128 + wc*64 + j*16 + (lane&15))*8;

    f32x4 acc[4][4];
    #pragma unroll
    for (int i=0;i<4;++i)
        #pragma unroll
        for (int j=0;j<4;++j) acc[i][j]=(f32x4){0.f,0.f,0.f,0.f};

#define STAGE(CUR) do { \
    async_load16(srcA0, &As[CUR][ia0*512]); \
    async_load16(srcA1, &As[CUR][ia1*512]); \
    async_load16(srcB0, &Bs[CUR][ia0*512]); \
    async_load16(srcB1, &Bs[CUR][ia1*512]); \
    srcA0+=64; srcA1+=64; srcB0+=BSTEP; srcB1+=BSTEP; } while(0)

    STAGE(0);
    asm volatile("s_waitcnt vmcnt(0)");
    __syncthreads();
    int cur=0;
    for (int t=0;t<NT;++t){
        if (t+1<NT) STAGE(cur^1);
        const short* Ab=As[cur]; const short* Bb=Bs[cur];
        bf16x8 af[4], bfv[4];
        #pragma unroll
        for (int i=0;i<4;++i) af[i]=*reinterpret_cast<const bf16x8*>(Ab + aoff[i]);
        #pragma unroll
        for (int j=0;j<4;++j) bfv[j]=*reinterpret_cast<const bf16x8*>(Bb + boff[j]);
        #pragma unroll
        for (int i=0;i<4;++i)
            #pragma unroll
            for (int j=0;j<4;++j)
                acc[i][j]=__builtin_amdgcn_mfma_f32_16x16x32_bf16(af[i],bfv[j],acc[i][j],0,0,0);
        __syncthreads();
        cur^=1;
    }
#undef STAGE

    int row0 = m0 + wr*64 + (lane>>4)*4;
    int colb = d0 + wc*64 + (lane&15);
    #pragma unroll
    for (int i=0;i<4;++i){
        #pragma unroll
        for (int q=0;q<4;++q){
            int m = row0 + i*16 + q;
            if (m < NN){
                size_t rb = ((size_t)b*NN+m)*DD;
                #pragma unroll
                for (int j=0;j<4;++j){
                    int d = colb + j*16;
                    h[rb+d] += acc[i][j][q] + sb[(lane&15)+j*16];
                }
            }
        }
    }
}

// ---------------- head ----------------
__global__ __launch_bounds__(256) void k_head(
    const float* __restrict__ h, const float* __restrict__ xf,
    const float* __restrict__ fw, const float* __restrict__ fbias,
    const float* __restrict__ hw, const float* __restrict__ hb,
    float* __restrict__ out)
{
    int bn=blockIdx.x; int tid=threadIdx.x; int lane=tid&63; int wv=tid>>6;
    __shared__ float fut[FD];
    __shared__ float fwl[HH*FFUT];
    __shared__ float fbl[HH];
    __shared__ float xfl[PP*FFUT];
    __shared__ float red[4][PP];
    for (int i=tid;i<HH*FFUT;i+=256) fwl[i]=fw[i];
    if (tid<HH) fbl[tid]=fbias[tid];
    for (int i=tid;i<PP*FFUT;i+=256) xfl[i]=xf[(size_t)bn*PP*FFUT+i];
    __syncthreads();
    for (int q=tid;q<FD;q+=256){
        int pp=q>>6, hh2=q&63;
        float v=fbl[hh2];
        #pragma unroll
        for (int c=0;c<FFUT;++c) v += xfl[pp*FFUT+c]*fwl[hh2*FFUT+c];
        fut[q]=v;
    }
    __syncthreads();
    float acc[PP];
    #pragma unroll
    for (int p=0;p<PP;++p) acc[p]=0.f;
    const float* hrow = h + (size_t)bn*DD;
    for (int d=tid; d<TOT; d+=256){
        float v = (d<DD)?hrow[d]:fut[d-DD];
        #pragma unroll
        for (int p=0;p<PP;++p) acc[p] += v*hw[(size_t)p*TOT+d];
    }
    #pragma unroll
    for (int p=0;p<PP;++p){
        float a=wave_sum64(acc[p]);
        if (lane==0) red[wv][p]=a;
    }
    __syncthreads();
    if (tid<PP) out[(size_t)bn*PP+tid] = red[0][tid]+red[1][tid]+red[2][tid]+red[3][tid] + hb[tid];
}

extern "C" void kernel_launch(void* const* d_in, const int* in_sizes, int n_in,
                              void* d_out, int out_size, void* d_ws, size_t ws_size,
                              hipStream_t stream)
{
    const float* x      = (const float*)d_in[0];
    const float* xfut   = (const float*)d_in[1];
    const float* adj    = (const float*)d_in[2];
    const float* fp_w   = (const float*)d_in[3];
    const float* fp_b   = (const float*)d_in[4];
    const float* inlng  = (const float*)d_in[5];
    const float* inlnb  = (const float*)d_in[6];
    const float* q_w    = (const float*)d_in[7];
    const float* q_b    = (const float*)d_in[8];
    const float* k_w    = (const float*)d_in[9];
    const float* k_b    = (const float*)d_in[10];
    const float* nemb   = (const float*)d_in[11];
    const float* galpha = (const float*)d_in[12];
    const float* wk     = (const float*)d_in[13];
    const float* mk     = (const float*)d_in[14];
    const float* lncg   = (const float*)d_in[15];
    const float* lncb   = (const float*)d_in[16];
    const float* lntg   = (const float*)d_in[17];
    const float* lntb   = (const float*)d_in[18];
    const float* lnfg   = (const float*)d_in[19];
    const float* lnfb   = (const float*)d_in[20];
    const float* lnsg   = (const float*)d_in[21];
    const float* lnsb   = (const float*)d_in[22];
    const float* tw     = (const float*)d_in[23];
    const float* tb     = (const float*)d_in[24];
    const float* fw     = (const float*)d_in[25];
    const float* fb     = (const float*)d_in[26];
    const float* sw     = (const float*)d_in[27];
    const float* sb     = (const float*)d_in[28];
    const float* futw   = (const float*)d_in[29];
    const float* futb   = (const float*)d_in[30];
    const float* hw     = (const float*)d_in[31];
    const float* hb     = (const float*)d_in[32];
    (void)in_sizes; (void)n_in; (void)out_size; (void)ws_size;
    float* out = (float*)d_out;
    float* ws = (float*)d_ws;
    const size_t HSZ = (size_t)BB*NN*SS*HH;

    float* h    = ws;
    float* embn = h + HSZ;
    float* ctx  = embn + (size_t)NN*HH;
    __hip_bfloat16* xpb   = (__hip_bfloat16*)(ctx + (size_t)BB*NN*HH);
    __hip_bfloat16* combh = xpb + HSZ;
    __hip_bfloat16* xpg   = combh + (size_t)BB*MP*KP;
    float* scores = (float*)xpg;   // aliased: scores dead before xpg is written
    unsigned short* wimg  = (unsigned short*)(xpg + (size_t)BB*(KP/8)*(size_t)DD*8);
    unsigned short* qpack = wimg + (size_t)NBLK*WIMG_SZ;
    unsigned short* kpack = qpack + (size_t)BB*8*MP*8;

    k_prepw<<<NBLK,256,0,stream>>>(wk, mk, tw, fw, sw, wimg);
    k_embnorm<<<NN,64,0,stream>>>(nemb, embn);
    k_front<<<BB*NN,256,0,stream>>>(x, fp_w, fp_b, inlng, inlnb, embn, h, ctx);
    k_qk<<<BB*NN,64,0,stream>>>(ctx, q_w,q_b,k_w,k_b, qpack, kpack);
    dim3 gqkt(MP/128, MP/128, BB);
    k_qkt<<<gqkt,256,0,stream>>>(qpack, kpack, scores);
    dim3 gtop(NN,BB);
    k_topk<<<gtop,256,0,stream>>>(scores, adj, galpha, combh);
    dim3 gpack(DD/256, KP/8, BB);
    dim3 gbmm(MP/128, DD/128, BB);
    for (int i=0;i<NBLK;++i){
        k_mixer2<<<BB*NN,256,0,stream>>>(h, xpb, wimg + (size_t)i*WIMG_SZ,
            lncg+i*HH,lncb+i*HH, lntg+i*HH,lntb+i*HH, lnfg+i*HH,lnfb+i*HH, lnsg+i*HH,lnsb+i*HH,
            tb+i*SS, fb+i*HH);
        k_pack_xp<<<gpack,256,0,stream>>>(xpb, xpg);
        k_bmm_mfma<<<gbmm,256,0,stream>>>(combh, xpg, sb+i*HH, h);
    }
    k_head<<<BB*NN,256,0,stream>>>(h, xfut, futw, futb, hw, hb, out);
}

// Round 5
// 726.711 us; speedup vs baseline: 5.8499x; 1.0675x over previous
//
#include <hip/hip_runtime.h>
#include <hip/hip_bf16.h>
#include <math.h>

#define BB 4
#define NN 1437
#define SS 56
#define PP 28
#define FIN 10
#define FFUT 6
#define HH 64
#define NBLK 2
#define TOPK 5
#define DD (SS*HH)     /* 3584 */
#define FD (PP*HH)     /* 1792 */
#define TOT (DD+FD)    /* 5376 */
#define MP 1536        /* padded M (12*128) */
#define KP 1472        /* padded K (46*32)  */
#define NT (KP/32)     /* 46 K-steps */
#define SP 1536        /* scores stride */
#define WIMG_SZ 16384  /* shorts per mixer-block weight image */

typedef __attribute__((ext_vector_type(8))) __bf16 bf16x8;
typedef __attribute__((ext_vector_type(4))) float  f32x4;

__device__ __forceinline__ float gelu_exact(float x){
    return 0.5f*x*(1.0f+erff(x*0.70710678118654752440f));
}
__device__ __forceinline__ float wave_sum64(float v){
    #pragma unroll
    for (int o=1;o<64;o<<=1) v += __shfl_xor(v,o,64);
    return v;
}
__device__ __forceinline__ void async_load16(const void* g, void* l){
    __builtin_amdgcn_global_load_lds(
        (const __attribute__((address_space(1))) void*)g,
        (__attribute__((address_space(3))) void*)l, 16, 0, 0);
}
__device__ __forceinline__ unsigned short f2bf(float x){
    unsigned int u = __float_as_uint(x);
    unsigned int r = (u + 0x7fffu + ((u>>16)&1u)) >> 16;
    return (unsigned short)r;
}
__device__ __forceinline__ unsigned long long umax64(unsigned long long a, unsigned long long b){return a>b?a:b;}
__device__ __forceinline__ unsigned long long umin64(unsigned long long a, unsigned long long b){return a<b?a:b;}

// ---------------- emb norm ----------------
__global__ __launch_bounds__(64) void k_embnorm(const float* __restrict__ emb,
                                                float* __restrict__ out){
    int n = blockIdx.x; int l = threadIdx.x;
    float v = emb[(size_t)n*HH+l];
    float ss = wave_sum64(v*v);
    float nrm = fmaxf(sqrtf(ss), 1e-12f);
    out[(size_t)n*HH+l] = v/nrm;
}

// ------- front: h = LN(x@fp_w^T+fp_b)+embn ; ctx = recency ctx -------
__global__ __launch_bounds__(256) void k_front(
    const float* __restrict__ x, const float* __restrict__ fpw, const float* __restrict__ fpb,
    const float* __restrict__ lng, const float* __restrict__ lnb,
    const float* __restrict__ embn, float* __restrict__ h, float* __restrict__ ctx)
{
    int bn = blockIdx.x; int n = bn % NN;
    int tid=threadIdx.x; int lane=tid&63; int wv=tid>>6;
    __shared__ float xin[SS*FIN];
    __shared__ float wlds[HH*FIN];
    __shared__ float rw[SS];
    __shared__ float rsum;
    __shared__ float red[4][HH];
    for (int i=tid;i<SS*FIN;i+=256) xin[i]=x[(size_t)bn*SS*FIN+i];
    for (int i=tid;i<HH*FIN;i+=256) wlds[i]=fpw[i];
    if (tid<SS) rw[tid]=expf(-(float)(SS-tid)/14.0f);
    __syncthreads();
    if (tid==0){ float s=0.f; for(int i=0;i<SS;++i) s+=rw[i]; rsum=s; }
    __syncthreads();
    float inv_rs = 1.0f/rsum;
    float gg=lng[lane], bv=lnb[lane], el=embn[(size_t)n*HH+lane], fb0=fpb[lane];
    float cacc=0.f;
    for (int s=wv;s<SS;s+=4){
        float v=fb0;
        #pragma unroll
        for (int c=0;c<FIN;++c) v += xin[s*FIN+c]*wlds[lane*FIN+c];
        float m = wave_sum64(v)*(1.f/HH);
        float d = v-m;
        float va = wave_sum64(d*d)*(1.f/HH);
        float hn = d*rsqrtf(va+1e-5f)*gg + bv + el;
        h[((size_t)bn*SS+s)*HH+lane]=hn;
        cacc += hn * rw[s]*inv_rs;
    }
    red[wv][lane]=cacc;
    __syncthreads();
    if (wv==0) ctx[(size_t)bn*HH+lane]=red[0][lane]+red[1][lane]+red[2][lane]+red[3][lane];
}

// ---------------- Q/K projections -> K-packed bf16 [b][8][MP][8] ----------------
__global__ __launch_bounds__(64) void k_qk(
    const float* __restrict__ ctx, const float* __restrict__ qw, const float* __restrict__ qb,
    const float* __restrict__ kw, const float* __restrict__ kb,
    unsigned short* __restrict__ qpack, unsigned short* __restrict__ kpack)
{
    __shared__ float wq[HH*65];
    __shared__ float wk2[HH*65];
    int lane=threadIdx.x; int bn=blockIdx.x;
    for (int i=lane;i<HH*HH;i+=64){ int hh=i>>6, kk=i&63; wq[kk*65+hh]=qw[i]; wk2[kk*65+hh]=kw[i]; }
    __syncthreads();
    const float* c = ctx + (size_t)bn*HH;
    float q=qb[lane], k=kb[lane];
    for (int kk=0;kk<HH;++kk){ float cv=c[kk]; q+=cv*wq[kk*65+lane]; k+=cv*wk2[kk*65+lane]; }
    int b = bn/NN, m = bn%NN;
    size_t off = (size_t)b*8*MP*8 + (size_t)(lane>>3)*MP*8 + (size_t)m*8 + (lane&7);
    qpack[off]=f2bf(q); kpack[off]=f2bf(k);
}

// ---------------- QK^T via MFMA -> scores = relu(clip(QK^T/8)) f32 ----------------
__global__ __launch_bounds__(256) void k_qkt(
    const unsigned short* __restrict__ qp, const unsigned short* __restrict__ kp,
    float* __restrict__ scores)
{
    int bm=blockIdx.x, bnn=blockIdx.y, b=blockIdx.z;
    int tid=threadIdx.x, lane=tid&63, wv=tid>>6;
    int g=lane>>4, c15=lane&15;
    int m0=bm*128, n0=bnn*128;
    __shared__ unsigned short As[8192];  // [8][128][8]
    __shared__ unsigned short Bs[8192];
    const char* qbase = (const char*)(qp + (size_t)b*8*MP*8);
    const char* kbase = (const char*)(kp + (size_t)b*8*MP*8);
    #pragma unroll
    for (int i=0;i<4;++i){
        int idx=i*256+tid; int ch=idx>>7, r=idx&127;
        async_load16(qbase + ((size_t)(ch*MP + m0 + r))*16, (char*)As + idx*16);
        async_load16(kbase + ((size_t)(ch*MP + n0 + r))*16, (char*)Bs + idx*16);
    }
    asm volatile("s_waitcnt vmcnt(0)");
    __syncthreads();
    int wr=wv>>1, wc=wv&1;
    f32x4 acc[4][4];
    #pragma unroll
    for (int i=0;i<4;++i)
        #pragma unroll
        for (int j=0;j<4;++j) acc[i][j]=(f32x4){0.f,0.f,0.f,0.f};
    #pragma unroll
    for (int kc=0;kc<2;++kc){
        bf16x8 af[4], bfv[4];
        #pragma unroll
        for (int i=0;i<4;++i)
            af[i]=*(const bf16x8*)((const char*)As + ((4*kc+g)*128 + wr*64+i*16+c15)*16);
        #pragma unroll
        for (int j=0;j<4;++j)
            bfv[j]=*(const bf16x8*)((const char*)Bs + ((4*kc+g)*128 + wc*64+j*16+c15)*16);
        #pragma unroll
        for (int i=0;i<4;++i)
            #pragma unroll
            for (int j=0;j<4;++j)
                acc[i][j]=__builtin_amdgcn_mfma_f32_16x16x32_bf16(af[i],bfv[j],acc[i][j],0,0,0);
    }
    #pragma unroll
    for (int i=0;i<4;++i){
        #pragma unroll
        for (int q=0;q<4;++q){
            int m = m0 + wr*64 + i*16 + g*4 + q;
            float* sr = scores + ((size_t)b*SP + m)*SP + n0 + wc*64 + c15;
            #pragma unroll
            for (int j=0;j<4;++j){
                float v = acc[i][j][q]*0.125f;
                v = fminf(fmaxf(v,0.f),10.f);
                sr[j*16]=v;
            }
        }
    }
}

// ---- top-5 + softmax + blend + L1 normalize -> comb bf16 [b][MP][KP] ----
#define INS(x) do{ unsigned long long t_=(x); \
    unsigned long long n0_=umax64(u0,t_), t1_=umin64(u0,t_); \
    unsigned long long n1_=umax64(u1,t1_), t2_=umin64(u1,t1_); \
    unsigned long long n2_=umax64(u2,t2_), t3_=umin64(u2,t2_); \
    unsigned long long n3_=umax64(u3,t3_), t4_=umin64(u3,t3_); \
    unsigned long long n4_=umax64(u4,t4_); \
    u0=n0_;u1=n1_;u2=n2_;u3=n3_;u4=n4_; }while(0)

#define MERGE(b0,b1,b2,b3,b4) do{ \
    unsigned long long o0_=umax64(u0,(b0)); \
    unsigned long long o1_=umax64(umax64((b1),umin64(u0,(b0))),u1); \
    unsigned long long o2_=umax64(umax64((b2),umin64(u0,(b1))),umax64(umin64(u1,(b0)),u2)); \
    unsigned long long o3_=umax64(umax64((b3),umin64(u0,(b2))),umax64(umin64(u1,(b1)),umax64(umin64(u2,(b0)),u3))); \
    unsigned long long o4_=umax64(umax64((b4),umin64(u0,(b3))),umax64(umax64(umin64(u1,(b2)),umin64(u2,(b1))),umax64(umin64(u3,(b0)),u4))); \
    u0=o0_;u1=o1_;u2=o2_;u3=o3_;u4=o4_; }while(0)

__global__ __launch_bounds__(256) void k_topk(
    const float* __restrict__ scores, const float* __restrict__ adj,
    const float* __restrict__ galpha, __hip_bfloat16* __restrict__ combh)
{
    int m=blockIdx.x, b=blockIdx.y, tid=threadIdx.x, lane=tid&63, wv=tid>>6;
    __shared__ float row[KP];
    __shared__ unsigned long long wtop[4][8];
    __shared__ float redp[4];
    const float* srow = scores + ((size_t)b*SP + m)*SP;
    unsigned long long u0=0,u1=0,u2=0,u3=0,u4=0;
    for (int n=tid;n<NN;n+=256){
        float v=srow[n];
        unsigned long long key=((unsigned long long)__float_as_uint(v)<<32)|(unsigned long long)(0xFFFFFFFFu-(unsigned)n);
        INS(key);
    }
    #pragma unroll
    for (int off=1; off<64; off<<=1){
        unsigned long long b0=__shfl_xor(u0,off,64), b1=__shfl_xor(u1,off,64),
                           b2=__shfl_xor(u2,off,64), b3=__shfl_xor(u3,off,64),
                           b4=__shfl_xor(u4,off,64);
        MERGE(b0,b1,b2,b3,b4);
    }
    if (lane==0){ wtop[wv][0]=u0; wtop[wv][1]=u1; wtop[wv][2]=u2; wtop[wv][3]=u3; wtop[wv][4]=u4; }
    __syncthreads();
    u0=wtop[0][0]; u1=wtop[0][1]; u2=wtop[0][2]; u3=wtop[0][3]; u4=wtop[0][4];
    #pragma unroll
    for (int w2=1;w2<4;++w2)
        MERGE(wtop[w2][0],wtop[w2][1],wtop[w2][2],wtop[w2][3],wtop[w2][4]);

    float s0=__uint_as_float((unsigned)(u0>>32)), s1=__uint_as_float((unsigned)(u1>>32)),
          s2=__uint_as_float((unsigned)(u2>>32)), s3=__uint_as_float((unsigned)(u3>>32)),
          s4=__uint_as_float((unsigned)(u4>>32));
    int i0=(int)(0xFFFFFFFFu-(unsigned)u0), i1=(int)(0xFFFFFFFFu-(unsigned)u1),
        i2=(int)(0xFFFFFFFFu-(unsigned)u2), i3=(int)(0xFFFFFFFFu-(unsigned)u3),
        i4=(int)(0xFFFFFFFFu-(unsigned)u4);
    float e0=1.f, e1=expf(s1-s0), e2=expf(s2-s0), e3=expf(s3-s0), e4=expf(s4-s0);
    float den=e0+e1+e2+e3+e4;
    float alpha=1.f/(1.f+expf(-galpha[0]));
    float oma=(1.f-alpha)/den;
    float p0=oma*e0, p1=oma*e1, p2=oma*e2, p3=oma*e3, p4=oma*e4;

    const float* arow = adj + (size_t)m*NN;
    float part=0.f;
    for (int n=tid;n<NN;n+=256){
        float v=alpha*arow[n];
        v += (n==i0)?p0:0.f;
        v += (n==i1)?p1:0.f;
        v += (n==i2)?p2:0.f;
        v += (n==i3)?p3:0.f;
        v += (n==i4)?p4:0.f;
        row[n]=v;
        part+=fabsf(v);
    }
    part=wave_sum64(part);
    if (lane==0) redp[wv]=part;
    __syncthreads();
    float inv=1.f/fmaxf(redp[0]+redp[1]+redp[2]+redp[3],1e-12f);
    __hip_bfloat16* dst = combh + ((size_t)b*MP+m)*KP;
    for (int n=tid;n<KP;n+=256){
        float v = (n<NN) ? row[n]*inv : 0.f;
        dst[n]=__float2bfloat16(v);
    }
}
#undef INS
#undef MERGE

// ---- prep: build per-mixer-block bf16 weight images ----
__global__ __launch_bounds__(256) void k_prepw(
    const float* __restrict__ wk, const float* __restrict__ mk,
    const float* __restrict__ tw, const float* __restrict__ fw,
    const float* __restrict__ sw, unsigned short* __restrict__ wimg)
{
    int i = blockIdx.x; int tid = threadIdx.x;
    const float* wki = wk + i*7;
    const float* mki = mk + i*28;
    const float* twi = tw + i*SS*SS;
    const float* fwi = fw + i*HH*HH;
    const float* swi = sw + i*HH*HH;
    unsigned short* o = wimg + (size_t)i*WIMG_SZ;
    for (int e=tid; e<4096; e+=256){
        int r = e>>6, k = e&63;
        int swz = ((k*2) ^ ((r&7)<<4)) >> 1;
        float mv = 0.f;
        if (r<SS && k<SS){
            int a = k-r+3;  if (a>=0 && a<7)  mv += wki[a];
            int b2= k-r+13; if (b2>=0 && b2<28) mv += mki[b2];
        }
        o[r*64 + swz] = f2bf(mv);
        float tv = (r<SS && k<SS) ? twi[r*SS+k] : 0.f;
        o[4096 + r*64 + swz] = f2bf(tv);
        int pk = (k>>3)*512 + r*8 + (k&7);
        o[8192  + pk] = f2bf(fwi[r*HH+k]);
        o[12288 + pk] = f2bf(swi[r*HH+k]);
    }
}

// ---- prep: head_w f32 [28][5376] -> bf16 [32][5376] (pad rows zero) ----
__global__ __launch_bounds__(256) void k_prep_head(
    const float* __restrict__ hw, __hip_bfloat16* __restrict__ hw16)
{
    int i = blockIdx.x*256 + threadIdx.x;   // 32*TOT total
    int r = i / TOT, k = i - r*TOT;
    float v = (r<PP) ? hw[(size_t)r*TOT + k] : 0.f;
    hw16[i] = __float2bfloat16(v);
}

// ---- fut: feats16[bn][3584+q] = bf16(x_future @ futw^T + futb) ----
__global__ __launch_bounds__(256) void k_fut(
    const float* __restrict__ xf, const float* __restrict__ fw,
    const float* __restrict__ fbias, __hip_bfloat16* __restrict__ feats)
{
    int bn=blockIdx.x, tid=threadIdx.x;
    __shared__ float fwl[HH*FFUT];
    __shared__ float fbl[HH];
    __shared__ float xfl[PP*FFUT];
    for (int i=tid;i<HH*FFUT;i+=256) fwl[i]=fw[i];
    if (tid<HH) fbl[tid]=fbias[tid];
    for (int i=tid;i<PP*FFUT;i+=256) xfl[i]=xf[(size_t)bn*PP*FFUT+i];
    __syncthreads();
    __hip_bfloat16* dst = feats + (size_t)bn*TOT + DD;
    for (int q=tid;q<FD;q+=256){
        int pp=q>>6, hh2=q&63;
        float v=fbl[hh2];
        #pragma unroll
        for (int c2=0;c2<FFUT;++c2) v += xfl[pp*FFUT+c2]*fwl[hh2*FFUT+c2];
        dst[q]=__float2bfloat16(v);
    }
}

// ---------------- MFMA mixer block ----------------
__global__ __launch_bounds__(256) void k_mixer2(
    float* __restrict__ h, __hip_bfloat16* __restrict__ xpb,
    const unsigned short* __restrict__ wimg,
    const float* __restrict__ lncg, const float* __restrict__ lncb,
    const float* __restrict__ lntg, const float* __restrict__ lntb,
    const float* __restrict__ lnfg, const float* __restrict__ lnfb,
    const float* __restrict__ lnsg, const float* __restrict__ lnsb,
    const float* __restrict__ tb, const float* __restrict__ fb)
{
    int bn=blockIdx.x, tid=threadIdx.x, lane=tid&63, w=tid>>6;
    int g=lane>>4, c=lane&15;
    __shared__ unsigned short wbuf[4][4096];
    __shared__ unsigned short xs[4096];
    __shared__ float prm[640];

    const char* wsrc=(const char*)wimg;
    char* wdst=(char*)&wbuf[0][0];
    #pragma unroll
    for (int i=0;i<8;++i)
        async_load16(wsrc+((size_t)(i*256+tid))*16, wdst+(i*256+w*64)*16);
    if (tid<64){
        prm[tid]      =lncg[tid]; prm[64+tid] =lncb[tid];
        prm[128+tid]  =lntg[tid]; prm[192+tid]=lntb[tid];
        prm[256+tid]  =lnfg[tid]; prm[320+tid]=lnfb[tid];
        prm[384+tid]  =lnsg[tid]; prm[448+tid]=lnsb[tid];
        prm[512+tid]  =(tid<SS)?tb[tid]:0.f;
        prm[576+tid]  =fb[tid];
    }
    float xl[4][4];
    float* hb = h + (size_t)bn*DD;
    int srow = 16*w + 4*g;
    #pragma unroll
    for (int q=0;q<4;++q){
        int s=srow+q;
        #pragma unroll
        for (int tj=0;tj<4;++tj)
            xl[q][tj] = (s<SS) ? hb[s*HH + tj*16 + c] : 0.f;
    }
    __syncthreads();

    float xn[4][4];
    f32x4 acc[4];

#define LNSTAGE(GOFF,BOFF) do{ \
    _Pragma("unroll") \
    for (int q=0;q<4;++q){ \
        float sv = xl[q][0]+xl[q][1]+xl[q][2]+xl[q][3]; \
        float s2 = xl[q][0]*xl[q][0]+xl[q][1]*xl[q][1]+xl[q][2]*xl[q][2]+xl[q][3]*xl[q][3]; \
        _Pragma("unroll") \
        for (int m2=1;m2<16;m2<<=1){ sv += __shfl_xor(sv,m2,64); s2 += __shfl_xor(s2,m2,64); } \
        float mn = sv*(1.f/64.f); \
        float var = s2*(1.f/64.f)-mn*mn; \
        float rstd = rsqrtf(var+1e-5f); \
        bool ok = (srow+q)<SS; \
        _Pragma("unroll") \
        for (int tj=0;tj<4;++tj){ \
            float v=(xl[q][tj]-mn)*rstd*prm[(GOFF)+tj*16+c]+prm[(BOFF)+tj*16+c]; \
            xn[q][tj]= ok ? v : 0.f; \
        } \
    } }while(0)

#define WRITE_XNP() do{ \
    _Pragma("unroll") \
    for (int qp=0;qp<2;++qp){ \
        int s0=srow+2*qp; \
        _Pragma("unroll") \
        for (int tj=0;tj<4;++tj){ \
            unsigned int pv=(unsigned int)f2bf(xn[2*qp][tj])|((unsigned int)f2bf(xn[2*qp+1][tj])<<16); \
            *(unsigned int*)((char*)xs + ((s0>>3)*1024 + (tj*16+c)*16 + (s0&7)*2)) = pv; \
        } \
    } }while(0)

#define WRITE_XNR() do{ \
    _Pragma("unroll") \
    for (int q=0;q<4;++q){ int s=srow+q; \
        _Pragma("unroll") \
        for (int tj=0;tj<4;++tj){ \
            *(unsigned short*)((char*)xs + s*128 + (((tj*16+c)*2) ^ ((s&7)<<4))) = f2bf(xn[q][tj]); \
        } \
    } }while(0)

#define MM(APTR,BPTR) do{ \
    _Pragma("unroll") \
    for (int tj=0;tj<4;++tj) acc[tj]=(f32x4){0.f,0.f,0.f,0.f}; \
    _Pragma("unroll") \
    for (int kc=0;kc<2;++kc){ \
        int arow=16*w+c; \
        bf16x8 af=*(const bf16x8*)((const char*)(APTR)+arow*128+((kc*64+g*16)^((arow&7)<<4))); \
        _Pragma("unroll") \
        for (int tj=0;tj<4;++tj){ \
            bf16x8 bf2=*(const bf16x8*)((const char*)(BPTR)+(kc*4+g)*1024+(tj*16+c)*16); \
            acc[tj]=__builtin_amdgcn_mfma_f32_16x16x32_bf16(af,bf2,acc[tj],0,0,0); \
        } \
    } }while(0)

    LNSTAGE(0,64); WRITE_XNP();
    __syncthreads();
    MM(&wbuf[0][0], xs);
    #pragma unroll
    for (int q=0;q<4;++q)
        #pragma unroll
        for (int tj=0;tj<4;++tj) xl[q][tj]+=acc[tj][q];
    __syncthreads();
    LNSTAGE(128,192); WRITE_XNP();
    __syncthreads();
    MM(&wbuf[1][0], xs);
    #pragma unroll
    for (int q=0;q<4;++q){
        float tbv=prm[512+srow+q];
        #pragma unroll
        for (int tj=0;tj<4;++tj) xl[q][tj]+=gelu_exact(acc[tj][q]+tbv);
    }
    __syncthreads();
    LNSTAGE(256,320); WRITE_XNR();
    __syncthreads();
    MM(xs, &wbuf[2][0]);
    #pragma unroll
    for (int q=0;q<4;++q)
        #pragma unroll
        for (int tj=0;tj<4;++tj) xl[q][tj]+=gelu_exact(acc[tj][q]+prm[576+tj*16+c]);
    __syncthreads();
    LNSTAGE(384,448); WRITE_XNR();
    __syncthreads();
    MM(xs, &wbuf[3][0]);
    __hip_bfloat16* xpo = xpb + (size_t)bn*DD;
    #pragma unroll
    for (int q=0;q<4;++q){
        int s=srow+q;
        if (s<SS){
            #pragma unroll
            for (int tj=0;tj<4;++tj){
                int d=s*HH+tj*16+c;
                hb[d]=xl[q][tj];
                xpo[d]=__float2bfloat16(acc[tj][q]);
            }
        }
    }
#undef LNSTAGE
#undef WRITE_XNP
#undef WRITE_XNR
#undef MM
}

// ---- pack xp bf16 [N][D] -> MFMA-ready [KP/8][D][8] with K zero-pad ----
__global__ __launch_bounds__(256) void k_pack_xp(
    const __hip_bfloat16* __restrict__ xpb, __hip_bfloat16* __restrict__ xpg)
{
    int d = blockIdx.x*256 + threadIdx.x;
    int kc = blockIdx.y; int b = blockIdx.z;
    union { __hip_bfloat16 hv[8]; float4 f4; } u;
    #pragma unroll
    for (int j=0;j<8;++j){
        int k = kc*8+j;
        u.hv[j] = (k<NN) ? xpb[((size_t)b*NN+k)*DD + d] : __float2bfloat16(0.f);
    }
    *reinterpret_cast<float4*>(&xpg[(((size_t)b*(KP/8)+kc)*DD + d)*8]) = u.f4;
}

// ---------------- spatial bmm via MFMA: h[b] += comb[b] @ xp[b] + sb ----------------
__global__ __launch_bounds__(256) void k_bmm_mfma(
    const __hip_bfloat16* __restrict__ combh,
    const __hip_bfloat16* __restrict__ xpg,
    const float* __restrict__ sb,
    float* __restrict__ h,
    __hip_bfloat16* __restrict__ h16)   // optional bf16 copy into feats16 (null to skip)
{
    int bm=blockIdx.x, bd=blockIdx.y, b=blockIdx.z;
    int tid=threadIdx.x; int lane=tid&63; int wv=tid>>6;
    int m0=bm*128, d0=bd*128;
    __shared__ short As[2][4096];
    __shared__ short Bs[2][4096];

    const char* cb = (const char*)(combh + (size_t)b*MP*KP);
    const char* xb = (const char*)(xpg   + (size_t)b*(KP/8)*(size_t)DD*8);

    int ia0 = wv*2, ia1 = wv*2+1;
    int g0 = ia0*64 + lane, g1 = ia1*64 + lane;
    const char* srcA0 = cb + ((size_t)(m0 + (g0&127))*KP + (g0>>7)*8)*2;
    const char* srcA1 = cb + ((size_t)(m0 + (g1&127))*KP + (g1>>7)*8)*2;
    const char* srcB0 = xb + ((size_t)(g0>>7)*DD + d0 + (g0&127))*16;
    const char* srcB1 = xb + ((size_t)(g1>>7)*DD + d0 + (g1&127))*16;
    const size_t BSTEP = (size_t)4*DD*16;

    int wr=wv>>1, wc=wv&1;
    int aoff[4], boff[4];
    #pragma unroll
    for (int i=0;i<4;++i) aoff[i] = ((lane>>4)*128 + wr*64 + i*16 + (lane&15))*8;
    #pragma unroll
    for (int j=0;j<4;++j) boff[j] = ((lane>>4)*128 + wc*64 + j*16 + (lane&15))*8;

    f32x4 acc[4][4];
    #pragma unroll
    for (int i=0;i<4;++i)
        #pragma unroll
        for (int j=0;j<4;++j) acc[i][j]=(f32x4){0.f,0.f,0.f,0.f};

#define STAGE(CUR) do { \
    async_load16(srcA0, &As[CUR][ia0*512]); \
    async_load16(srcA1, &As[CUR][ia1*512]); \
    async_load16(srcB0, &Bs[CUR][ia0*512]); \
    async_load16(srcB1, &Bs[CUR][ia1*512]); \
    srcA0+=64; srcA1+=64; srcB0+=BSTEP; srcB1+=BSTEP; } while(0)

    STAGE(0);
    asm volatile("s_waitcnt vmcnt(0)");
    __syncthreads();
    int cur=0;
    for (int t=0;t<NT;++t){
        if (t+1<NT) STAGE(cur^1);
        const short* Ab=As[cur]; const short* Bb=Bs[cur];
        bf16x8 af[4], bfv[4];
        #pragma unroll
        for (int i=0;i<4;++i) af[i]=*reinterpret_cast<const bf16x8*>(Ab + aoff[i]);
        #pragma unroll
        for (int j=0;j<4;++j) bfv[j]=*reinterpret_cast<const bf16x8*>(Bb + boff[j]);
        #pragma unroll
        for (int i=0;i<4;++i)
            #pragma unroll
            for (int j=0;j<4;++j)
                acc[i][j]=__builtin_amdgcn_mfma_f32_16x16x32_bf16(af[i],bfv[j],acc[i][j],0,0,0);
        __syncthreads();
        cur^=1;
    }
#undef STAGE

    int row0 = m0 + wr*64 + (lane>>4)*4;
    int colb = d0 + wc*64 + (lane&15);
    #pragma unroll
    for (int i=0;i<4;++i){
        #pragma unroll
        for (int q=0;q<4;++q){
            int m = row0 + i*16 + q;
            if (m < NN){
                size_t rb = ((size_t)b*NN+m)*DD;
                #pragma unroll
                for (int j=0;j<4;++j){
                    int d = colb + j*16;
                    float nv = h[rb+d] + acc[i][j][q] + sb[(lane&15)+j*16];
                    h[rb+d] = nv;
                    if (h16) h16[((size_t)b*NN+m)*TOT + d] = __float2bfloat16(nv);
                }
            }
        }
    }
}

// ---------------- head GEMM: out = feats16 @ hw16^T + hb ----------------
__global__ __launch_bounds__(256) void k_head_mfma(
    const __hip_bfloat16* __restrict__ feats, const __hip_bfloat16* __restrict__ hw16,
    const float* __restrict__ hb, float* __restrict__ out)
{
    int tid=threadIdx.x, lane=tid&63, w=tid>>6;
    int g=lane>>4, c=lane&15;
    int m0=blockIdx.x*32;
    int rt=w>>1, pt=w&1;
    int arow = m0 + rt*16 + c;
    if (arow > BB*NN-1) arow = BB*NN-1;
    const char* abase = (const char*)feats + (size_t)arow*TOT*2 + g*16;
    const char* bbase = (const char*)hw16 + (size_t)(pt*16+c)*TOT*2 + g*16;
    f32x4 acc=(f32x4){0.f,0.f,0.f,0.f};
    #pragma unroll 4
    for (int kc=0;kc<TOT/32;++kc){
        bf16x8 af =*(const bf16x8*)(abase + (size_t)kc*64);
        bf16x8 bf2=*(const bf16x8*)(bbase + (size_t)kc*64);
        acc=__builtin_amdgcn_mfma_f32_16x16x32_bf16(af,bf2,acc,0,0,0);
    }
    int col = pt*16 + c;
    #pragma unroll
    for (int q=0;q<4;++q){
        int row = m0 + rt*16 + g*4 + q;
        if (row < BB*NN && col < PP)
            out[(size_t)row*PP + col] = acc[q] + hb[col];
    }
}

extern "C" void kernel_launch(void* const* d_in, const int* in_sizes, int n_in,
                              void* d_out, int out_size, void* d_ws, size_t ws_size,
                              hipStream_t stream)
{
    const float* x      = (const float*)d_in[0];
    const float* xfut   = (const float*)d_in[1];
    const float* adj    = (const float*)d_in[2];
    const float* fp_w   = (const float*)d_in[3];
    const float* fp_b   = (const float*)d_in[4];
    const float* inlng  = (const float*)d_in[5];
    const float* inlnb  = (const float*)d_in[6];
    const float* q_w    = (const float*)d_in[7];
    const float* q_b    = (const float*)d_in[8];
    const float* k_w    = (const float*)d_in[9];
    const float* k_b    = (const float*)d_in[10];
    const float* nemb   = (const float*)d_in[11];
    const float* galpha = (const float*)d_in[12];
    const float* wk     = (const float*)d_in[13];
    const float* mk     = (const float*)d_in[14];
    const float* lncg   = (const float*)d_in[15];
    const float* lncb   = (const float*)d_in[16];
    const float* lntg   = (const float*)d_in[17];
    const float* lntb   = (const float*)d_in[18];
    const float* lnfg   = (const float*)d_in[19];
    const float* lnfb   = (const float*)d_in[20];
    const float* lnsg   = (const float*)d_in[21];
    const float* lnsb   = (const float*)d_in[22];
    const float* tw     = (const float*)d_in[23];
    const float* tb     = (const float*)d_in[24];
    const float* fw     = (const float*)d_in[25];
    const float* fb     = (const float*)d_in[26];
    const float* sw     = (const float*)d_in[27];
    const float* sb     = (const float*)d_in[28];
    const float* futw   = (const float*)d_in[29];
    const float* futb   = (const float*)d_in[30];
    const float* hw     = (const float*)d_in[31];
    const float* hb     = (const float*)d_in[32];
    (void)in_sizes; (void)n_in; (void)out_size; (void)ws_size;
    float* out = (float*)d_out;
    float* ws = (float*)d_ws;
    const size_t HSZ = (size_t)BB*NN*SS*HH;

    float* h    = ws;
    float* embn = h + HSZ;
    float* ctx  = embn + (size_t)NN*HH;
    __hip_bfloat16* xpb   = (__hip_bfloat16*)(ctx + (size_t)BB*NN*HH);
    __hip_bfloat16* combh = xpb + HSZ;
    __hip_bfloat16* xpg   = combh + (size_t)BB*MP*KP;
    float* scores = (float*)xpg;   // aliased: scores dead before xpg is written
    unsigned short* wimg  = (unsigned short*)(xpg + (size_t)BB*(KP/8)*(size_t)DD*8);
    unsigned short* qpack = wimg + (size_t)NBLK*WIMG_SZ;
    unsigned short* kpack = qpack + (size_t)BB*8*MP*8;
    __hip_bfloat16* feats16 = (__hip_bfloat16*)(kpack + (size_t)BB*8*MP*8);
    __hip_bfloat16* hw16    = feats16 + (size_t)BB*NN*TOT;

    k_prepw<<<NBLK,256,0,stream>>>(wk, mk, tw, fw, sw, wimg);
    k_prep_head<<<(32*TOT)/256,256,0,stream>>>(hw, hw16);
    k_fut<<<BB*NN,256,0,stream>>>(xfut, futw, futb, feats16);
    k_embnorm<<<NN,64,0,stream>>>(nemb, embn);
    k_front<<<BB*NN,256,0,stream>>>(x, fp_w, fp_b, inlng, inlnb, embn, h, ctx);
    k_qk<<<BB*NN,64,0,stream>>>(ctx, q_w,q_b,k_w,k_b, qpack, kpack);
    dim3 gqkt(MP/128, MP/128, BB);
    k_qkt<<<gqkt,256,0,stream>>>(qpack, kpack, scores);
    dim3 gtop(NN,BB);
    k_topk<<<gtop,256,0,stream>>>(scores, adj, galpha, combh);
    dim3 gpack(DD/256, KP/8, BB);
    dim3 gbmm(MP/128, DD/128, BB);
    for (int i=0;i<NBLK;++i){
        k_mixer2<<<BB*NN,256,0,stream>>>(h, xpb, wimg + (size_t)i*WIMG_SZ,
            lncg+i*HH,lncb+i*HH, lntg+i*HH,lntb+i*HH, lnfg+i*HH,lnfb+i*HH, lnsg+i*HH,lnsb+i*HH,
            tb+i*SS, fb+i*HH);
        k_pack_xp<<<gpack,256,0,stream>>>(xpb, xpg);
        k_bmm_mfma<<<gbmm,256,0,stream>>>(combh, xpg, sb+i*HH, h,
            (i==NBLK-1) ? feats16 : (__hip_bfloat16*)nullptr);
    }
    k_head_mfma<<<(BB*NN+31)/32,256,0,stream>>>(feats16, hw16, hb, out);
}

// Round 6
// 691.053 us; speedup vs baseline: 6.1518x; 1.0516x over previous
//
#include <hip/hip_runtime.h>
#include <hip/hip_bf16.h>
#include <math.h>

#define BB 4
#define NN 1437
#define SS 56
#define PP 28
#define FIN 10
#define FFUT 6
#define HH 64
#define NBLK 2
#define TOPK 5
#define DD (SS*HH)     /* 3584 */
#define FD (PP*HH)     /* 1792 */
#define TOT (DD+FD)    /* 5376 */
#define MP 1536        /* padded M (12*128) */
#define KP 1472        /* padded K (46*32)  */
#define NT (KP/32)     /* 46 K-steps */
#define SP 1536        /* scores stride */
#define WIMG_SZ 16384  /* shorts per mixer-block weight image */

typedef __attribute__((ext_vector_type(8))) __bf16 bf16x8;
typedef __attribute__((ext_vector_type(4))) float  f32x4;

__device__ __forceinline__ float gelu_exact(float x){
    return 0.5f*x*(1.0f+erff(x*0.70710678118654752440f));
}
__device__ __forceinline__ float wave_sum64(float v){
    #pragma unroll
    for (int o=1;o<64;o<<=1) v += __shfl_xor(v,o,64);
    return v;
}
__device__ __forceinline__ void async_load16(const void* g, void* l){
    __builtin_amdgcn_global_load_lds(
        (const __attribute__((address_space(1))) void*)g,
        (__attribute__((address_space(3))) void*)l, 16, 0, 0);
}
__device__ __forceinline__ unsigned short f2bf(float x){
    unsigned int u = __float_as_uint(x);
    unsigned int r = (u + 0x7fffu + ((u>>16)&1u)) >> 16;
    return (unsigned short)r;
}
__device__ __forceinline__ unsigned long long umax64(unsigned long long a, unsigned long long b){return a>b?a:b;}
__device__ __forceinline__ unsigned long long umin64(unsigned long long a, unsigned long long b){return a<b?a:b;}

// ---------------- emb norm ----------------
__global__ __launch_bounds__(64) void k_embnorm(const float* __restrict__ emb,
                                                float* __restrict__ out){
    int n = blockIdx.x; int l = threadIdx.x;
    float v = emb[(size_t)n*HH+l];
    float ss = wave_sum64(v*v);
    float nrm = fmaxf(sqrtf(ss), 1e-12f);
    out[(size_t)n*HH+l] = v/nrm;
}

// ------- front: h = LN(x@fp_w^T+fp_b)+embn ; ctx = recency ctx -------
__global__ __launch_bounds__(256) void k_front(
    const float* __restrict__ x, const float* __restrict__ fpw, const float* __restrict__ fpb,
    const float* __restrict__ lng, const float* __restrict__ lnb,
    const float* __restrict__ embn, float* __restrict__ h, float* __restrict__ ctx)
{
    int bn = blockIdx.x; int n = bn % NN;
    int tid=threadIdx.x; int lane=tid&63; int wv=tid>>6;
    __shared__ float xin[SS*FIN];
    __shared__ float wlds[HH*FIN];
    __shared__ float rw[SS];
    __shared__ float rsum;
    __shared__ float red[4][HH];
    for (int i=tid;i<SS*FIN;i+=256) xin[i]=x[(size_t)bn*SS*FIN+i];
    for (int i=tid;i<HH*FIN;i+=256) wlds[i]=fpw[i];
    if (tid<SS) rw[tid]=expf(-(float)(SS-tid)/14.0f);
    __syncthreads();
    if (tid==0){ float s=0.f; for(int i=0;i<SS;++i) s+=rw[i]; rsum=s; }
    __syncthreads();
    float inv_rs = 1.0f/rsum;
    float gg=lng[lane], bv=lnb[lane], el=embn[(size_t)n*HH+lane], fb0=fpb[lane];
    float cacc=0.f;
    for (int s=wv;s<SS;s+=4){
        float v=fb0;
        #pragma unroll
        for (int c=0;c<FIN;++c) v += xin[s*FIN+c]*wlds[lane*FIN+c];
        float m = wave_sum64(v)*(1.f/HH);
        float d = v-m;
        float va = wave_sum64(d*d)*(1.f/HH);
        float hn = d*rsqrtf(va+1e-5f)*gg + bv + el;
        h[((size_t)bn*SS+s)*HH+lane]=hn;
        cacc += hn * rw[s]*inv_rs;
    }
    red[wv][lane]=cacc;
    __syncthreads();
    if (wv==0) ctx[(size_t)bn*HH+lane]=red[0][lane]+red[1][lane]+red[2][lane]+red[3][lane];
}

// ---------------- Q/K projections -> K-packed bf16 [b][8][MP][8] ----------------
__global__ __launch_bounds__(64) void k_qk(
    const float* __restrict__ ctx, const float* __restrict__ qw, const float* __restrict__ qb,
    const float* __restrict__ kw, const float* __restrict__ kb,
    unsigned short* __restrict__ qpack, unsigned short* __restrict__ kpack)
{
    __shared__ float wq[HH*65];
    __shared__ float wk2[HH*65];
    int lane=threadIdx.x; int bn=blockIdx.x;
    for (int i=lane;i<HH*HH;i+=64){ int hh=i>>6, kk=i&63; wq[kk*65+hh]=qw[i]; wk2[kk*65+hh]=kw[i]; }
    __syncthreads();
    const float* c = ctx + (size_t)bn*HH;
    float q=qb[lane], k=kb[lane];
    for (int kk=0;kk<HH;++kk){ float cv=c[kk]; q+=cv*wq[kk*65+lane]; k+=cv*wk2[kk*65+lane]; }
    int b = bn/NN, m = bn%NN;
    size_t off = (size_t)b*8*MP*8 + (size_t)(lane>>3)*MP*8 + (size_t)m*8 + (lane&7);
    qpack[off]=f2bf(q); kpack[off]=f2bf(k);
}

// ---------------- QK^T via MFMA -> scores = relu(clip(QK^T/8)) f32 ----------------
__global__ __launch_bounds__(256) void k_qkt(
    const unsigned short* __restrict__ qp, const unsigned short* __restrict__ kp,
    float* __restrict__ scores)
{
    int bm=blockIdx.x, bnn=blockIdx.y, b=blockIdx.z;
    int tid=threadIdx.x, lane=tid&63, wv=tid>>6;
    int g=lane>>4, c15=lane&15;
    int m0=bm*128, n0=bnn*128;
    __shared__ unsigned short As[8192];  // [8][128][8]
    __shared__ unsigned short Bs[8192];
    const char* qbase = (const char*)(qp + (size_t)b*8*MP*8);
    const char* kbase = (const char*)(kp + (size_t)b*8*MP*8);
    #pragma unroll
    for (int i=0;i<4;++i){
        int idx=i*256+tid; int ch=idx>>7, r=idx&127;
        async_load16(qbase + ((size_t)(ch*MP + m0 + r))*16, (char*)As + idx*16);
        async_load16(kbase + ((size_t)(ch*MP + n0 + r))*16, (char*)Bs + idx*16);
    }
    asm volatile("s_waitcnt vmcnt(0)");
    __syncthreads();
    int wr=wv>>1, wc=wv&1;
    f32x4 acc[4][4];
    #pragma unroll
    for (int i=0;i<4;++i)
        #pragma unroll
        for (int j=0;j<4;++j) acc[i][j]=(f32x4){0.f,0.f,0.f,0.f};
    #pragma unroll
    for (int kc=0;kc<2;++kc){
        bf16x8 af[4], bfv[4];
        #pragma unroll
        for (int i=0;i<4;++i)
            af[i]=*(const bf16x8*)((const char*)As + ((4*kc+g)*128 + wr*64+i*16+c15)*16);
        #pragma unroll
        for (int j=0;j<4;++j)
            bfv[j]=*(const bf16x8*)((const char*)Bs + ((4*kc+g)*128 + wc*64+j*16+c15)*16);
        #pragma unroll
        for (int i=0;i<4;++i)
            #pragma unroll
            for (int j=0;j<4;++j)
                acc[i][j]=__builtin_amdgcn_mfma_f32_16x16x32_bf16(af[i],bfv[j],acc[i][j],0,0,0);
    }
    #pragma unroll
    for (int i=0;i<4;++i){
        #pragma unroll
        for (int q=0;q<4;++q){
            int m = m0 + wr*64 + i*16 + g*4 + q;
            float* sr = scores + ((size_t)b*SP + m)*SP + n0 + wc*64 + c15;
            #pragma unroll
            for (int j=0;j<4;++j){
                float v = acc[i][j][q]*0.125f;
                v = fminf(fmaxf(v,0.f),10.f);
                sr[j*16]=v;
            }
        }
    }
}

// ---- top-5 + softmax + blend + L1 normalize -> comb bf16 [b][MP][KP] ----
#define INS(x) do{ unsigned long long t_=(x); \
    unsigned long long n0_=umax64(u0,t_), t1_=umin64(u0,t_); \
    unsigned long long n1_=umax64(u1,t1_), t2_=umin64(u1,t1_); \
    unsigned long long n2_=umax64(u2,t2_), t3_=umin64(u2,t2_); \
    unsigned long long n3_=umax64(u3,t3_), t4_=umin64(u3,t3_); \
    unsigned long long n4_=umax64(u4,t4_); \
    u0=n0_;u1=n1_;u2=n2_;u3=n3_;u4=n4_; }while(0)

#define MERGE(b0,b1,b2,b3,b4) do{ \
    unsigned long long o0_=umax64(u0,(b0)); \
    unsigned long long o1_=umax64(umax64((b1),umin64(u0,(b0))),u1); \
    unsigned long long o2_=umax64(umax64((b2),umin64(u0,(b1))),umax64(umin64(u1,(b0)),u2)); \
    unsigned long long o3_=umax64(umax64((b3),umin64(u0,(b2))),umax64(umin64(u1,(b1)),umax64(umin64(u2,(b0)),u3))); \
    unsigned long long o4_=umax64(umax64((b4),umin64(u0,(b3))),umax64(umax64(umin64(u1,(b2)),umin64(u2,(b1))),umax64(umin64(u3,(b0)),u4))); \
    u0=o0_;u1=o1_;u2=o2_;u3=o3_;u4=o4_; }while(0)

__global__ __launch_bounds__(256) void k_topk(
    const float* __restrict__ scores, const float* __restrict__ adj,
    const float* __restrict__ galpha, __hip_bfloat16* __restrict__ combh)
{
    int m=blockIdx.x, b=blockIdx.y, tid=threadIdx.x, lane=tid&63, wv=tid>>6;
    __shared__ float row[KP];
    __shared__ unsigned long long wtop[4][8];
    __shared__ float redp[4];
    const float* srow = scores + ((size_t)b*SP + m)*SP;
    unsigned long long u0=0,u1=0,u2=0,u3=0,u4=0;
    for (int n=tid;n<NN;n+=256){
        float v=srow[n];
        unsigned long long key=((unsigned long long)__float_as_uint(v)<<32)|(unsigned long long)(0xFFFFFFFFu-(unsigned)n);
        INS(key);
    }
    #pragma unroll
    for (int off=1; off<64; off<<=1){
        unsigned long long b0=__shfl_xor(u0,off,64), b1=__shfl_xor(u1,off,64),
                           b2=__shfl_xor(u2,off,64), b3=__shfl_xor(u3,off,64),
                           b4=__shfl_xor(u4,off,64);
        MERGE(b0,b1,b2,b3,b4);
    }
    if (lane==0){ wtop[wv][0]=u0; wtop[wv][1]=u1; wtop[wv][2]=u2; wtop[wv][3]=u3; wtop[wv][4]=u4; }
    __syncthreads();
    u0=wtop[0][0]; u1=wtop[0][1]; u2=wtop[0][2]; u3=wtop[0][3]; u4=wtop[0][4];
    #pragma unroll
    for (int w2=1;w2<4;++w2)
        MERGE(wtop[w2][0],wtop[w2][1],wtop[w2][2],wtop[w2][3],wtop[w2][4]);

    float s0=__uint_as_float((unsigned)(u0>>32)), s1=__uint_as_float((unsigned)(u1>>32)),
          s2=__uint_as_float((unsigned)(u2>>32)), s3=__uint_as_float((unsigned)(u3>>32)),
          s4=__uint_as_float((unsigned)(u4>>32));
    int i0=(int)(0xFFFFFFFFu-(unsigned)u0), i1=(int)(0xFFFFFFFFu-(unsigned)u1),
        i2=(int)(0xFFFFFFFFu-(unsigned)u2), i3=(int)(0xFFFFFFFFu-(unsigned)u3),
        i4=(int)(0xFFFFFFFFu-(unsigned)u4);
    float e0=1.f, e1=expf(s1-s0), e2=expf(s2-s0), e3=expf(s3-s0), e4=expf(s4-s0);
    float den=e0+e1+e2+e3+e4;
    float alpha=1.f/(1.f+expf(-galpha[0]));
    float oma=(1.f-alpha)/den;
    float p0=oma*e0, p1=oma*e1, p2=oma*e2, p3=oma*e3, p4=oma*e4;

    const float* arow = adj + (size_t)m*NN;
    float part=0.f;
    for (int n=tid;n<NN;n+=256){
        float v=alpha*arow[n];
        v += (n==i0)?p0:0.f;
        v += (n==i1)?p1:0.f;
        v += (n==i2)?p2:0.f;
        v += (n==i3)?p3:0.f;
        v += (n==i4)?p4:0.f;
        row[n]=v;
        part+=fabsf(v);
    }
    part=wave_sum64(part);
    if (lane==0) redp[wv]=part;
    __syncthreads();
    float inv=1.f/fmaxf(redp[0]+redp[1]+redp[2]+redp[3],1e-12f);
    __hip_bfloat16* dst = combh + ((size_t)b*MP+m)*KP;
    for (int n=tid;n<KP;n+=256){
        float v = (n<NN) ? row[n]*inv : 0.f;
        dst[n]=__float2bfloat16(v);
    }
}
#undef INS
#undef MERGE

// ---- prep: build per-mixer-block bf16 weight images ----
__global__ __launch_bounds__(256) void k_prepw(
    const float* __restrict__ wk, const float* __restrict__ mk,
    const float* __restrict__ tw, const float* __restrict__ fw,
    const float* __restrict__ sw, unsigned short* __restrict__ wimg)
{
    int i = blockIdx.x; int tid = threadIdx.x;
    const float* wki = wk + i*7;
    const float* mki = mk + i*28;
    const float* twi = tw + i*SS*SS;
    const float* fwi = fw + i*HH*HH;
    const float* swi = sw + i*HH*HH;
    unsigned short* o = wimg + (size_t)i*WIMG_SZ;
    for (int e=tid; e<4096; e+=256){
        int r = e>>6, k = e&63;
        int swz = ((k*2) ^ ((r&7)<<4)) >> 1;
        float mv = 0.f;
        if (r<SS && k<SS){
            int a = k-r+3;  if (a>=0 && a<7)  mv += wki[a];
            int b2= k-r+13; if (b2>=0 && b2<28) mv += mki[b2];
        }
        o[r*64 + swz] = f2bf(mv);
        float tv = (r<SS && k<SS) ? twi[r*SS+k] : 0.f;
        o[4096 + r*64 + swz] = f2bf(tv);
        int pk = (k>>3)*512 + r*8 + (k&7);
        o[8192  + pk] = f2bf(fwi[r*HH+k]);
        o[12288 + pk] = f2bf(swi[r*HH+k]);
    }
}

// ---- prep: head_w f32 [28][5376] -> bf16 [32][5376] (pad rows zero) ----
__global__ __launch_bounds__(256) void k_prep_head(
    const float* __restrict__ hw, __hip_bfloat16* __restrict__ hw16)
{
    int i = blockIdx.x*256 + threadIdx.x;   // 32*TOT total
    int r = i / TOT, k = i - r*TOT;
    float v = (r<PP) ? hw[(size_t)r*TOT + k] : 0.f;
    hw16[i] = __float2bfloat16(v);
}

// ---- fut: feats16[bn][3584+q] = bf16(x_future @ futw^T + futb) ----
__global__ __launch_bounds__(256) void k_fut(
    const float* __restrict__ xf, const float* __restrict__ fw,
    const float* __restrict__ fbias, __hip_bfloat16* __restrict__ feats)
{
    int bn=blockIdx.x, tid=threadIdx.x;
    __shared__ float fwl[HH*FFUT];
    __shared__ float fbl[HH];
    __shared__ float xfl[PP*FFUT];
    for (int i=tid;i<HH*FFUT;i+=256) fwl[i]=fw[i];
    if (tid<HH) fbl[tid]=fbias[tid];
    for (int i=tid;i<PP*FFUT;i+=256) xfl[i]=xf[(size_t)bn*PP*FFUT+i];
    __syncthreads();
    __hip_bfloat16* dst = feats + (size_t)bn*TOT + DD;
    for (int q=tid;q<FD;q+=256){
        int pp=q>>6, hh2=q&63;
        float v=fbl[hh2];
        #pragma unroll
        for (int c2=0;c2<FFUT;++c2) v += xfl[pp*FFUT+c2]*fwl[hh2*FFUT+c2];
        dst[q]=__float2bfloat16(v);
    }
}

// ---------------- MFMA mixer block ----------------
__global__ __launch_bounds__(256) void k_mixer2(
    float* __restrict__ h, __hip_bfloat16* __restrict__ xpb,
    const unsigned short* __restrict__ wimg,
    const float* __restrict__ lncg, const float* __restrict__ lncb,
    const float* __restrict__ lntg, const float* __restrict__ lntb,
    const float* __restrict__ lnfg, const float* __restrict__ lnfb,
    const float* __restrict__ lnsg, const float* __restrict__ lnsb,
    const float* __restrict__ tb, const float* __restrict__ fb)
{
    int bn=blockIdx.x, tid=threadIdx.x, lane=tid&63, w=tid>>6;
    int g=lane>>4, c=lane&15;
    __shared__ unsigned short wbuf[4][4096];
    __shared__ unsigned short xs[4096];
    __shared__ float prm[640];

    const char* wsrc=(const char*)wimg;
    char* wdst=(char*)&wbuf[0][0];
    #pragma unroll
    for (int i=0;i<8;++i)
        async_load16(wsrc+((size_t)(i*256+tid))*16, wdst+(i*256+w*64)*16);
    if (tid<64){
        prm[tid]      =lncg[tid]; prm[64+tid] =lncb[tid];
        prm[128+tid]  =lntg[tid]; prm[192+tid]=lntb[tid];
        prm[256+tid]  =lnfg[tid]; prm[320+tid]=lnfb[tid];
        prm[384+tid]  =lnsg[tid]; prm[448+tid]=lnsb[tid];
        prm[512+tid]  =(tid<SS)?tb[tid]:0.f;
        prm[576+tid]  =fb[tid];
    }
    float xl[4][4];
    float* hb = h + (size_t)bn*DD;
    int srow = 16*w + 4*g;
    #pragma unroll
    for (int q=0;q<4;++q){
        int s=srow+q;
        #pragma unroll
        for (int tj=0;tj<4;++tj)
            xl[q][tj] = (s<SS) ? hb[s*HH + tj*16 + c] : 0.f;
    }
    __syncthreads();

    float xn[4][4];
    f32x4 acc[4];

#define LNSTAGE(GOFF,BOFF) do{ \
    _Pragma("unroll") \
    for (int q=0;q<4;++q){ \
        float sv = xl[q][0]+xl[q][1]+xl[q][2]+xl[q][3]; \
        float s2 = xl[q][0]*xl[q][0]+xl[q][1]*xl[q][1]+xl[q][2]*xl[q][2]+xl[q][3]*xl[q][3]; \
        _Pragma("unroll") \
        for (int m2=1;m2<16;m2<<=1){ sv += __shfl_xor(sv,m2,64); s2 += __shfl_xor(s2,m2,64); } \
        float mn = sv*(1.f/64.f); \
        float var = s2*(1.f/64.f)-mn*mn; \
        float rstd = rsqrtf(var+1e-5f); \
        bool ok = (srow+q)<SS; \
        _Pragma("unroll") \
        for (int tj=0;tj<4;++tj){ \
            float v=(xl[q][tj]-mn)*rstd*prm[(GOFF)+tj*16+c]+prm[(BOFF)+tj*16+c]; \
            xn[q][tj]= ok ? v : 0.f; \
        } \
    } }while(0)

#define WRITE_XNP() do{ \
    _Pragma("unroll") \
    for (int qp=0;qp<2;++qp){ \
        int s0=srow+2*qp; \
        _Pragma("unroll") \
        for (int tj=0;tj<4;++tj){ \
            unsigned int pv=(unsigned int)f2bf(xn[2*qp][tj])|((unsigned int)f2bf(xn[2*qp+1][tj])<<16); \
            *(unsigned int*)((char*)xs + ((s0>>3)*1024 + (tj*16+c)*16 + (s0&7)*2)) = pv; \
        } \
    } }while(0)

#define WRITE_XNR() do{ \
    _Pragma("unroll") \
    for (int q=0;q<4;++q){ int s=srow+q; \
        _Pragma("unroll") \
        for (int tj=0;tj<4;++tj){ \
            *(unsigned short*)((char*)xs + s*128 + (((tj*16+c)*2) ^ ((s&7)<<4))) = f2bf(xn[q][tj]); \
        } \
    } }while(0)

#define MM(APTR,BPTR) do{ \
    _Pragma("unroll") \
    for (int tj=0;tj<4;++tj) acc[tj]=(f32x4){0.f,0.f,0.f,0.f}; \
    _Pragma("unroll") \
    for (int kc=0;kc<2;++kc){ \
        int arow=16*w+c; \
        bf16x8 af=*(const bf16x8*)((const char*)(APTR)+arow*128+((kc*64+g*16)^((arow&7)<<4))); \
        _Pragma("unroll") \
        for (int tj=0;tj<4;++tj){ \
            bf16x8 bf2=*(const bf16x8*)((const char*)(BPTR)+(kc*4+g)*1024+(tj*16+c)*16); \
            acc[tj]=__builtin_amdgcn_mfma_f32_16x16x32_bf16(af,bf2,acc[tj],0,0,0); \
        } \
    } }while(0)

    LNSTAGE(0,64); WRITE_XNP();
    __syncthreads();
    MM(&wbuf[0][0], xs);
    #pragma unroll
    for (int q=0;q<4;++q)
        #pragma unroll
        for (int tj=0;tj<4;++tj) xl[q][tj]+=acc[tj][q];
    __syncthreads();
    LNSTAGE(128,192); WRITE_XNP();
    __syncthreads();
    MM(&wbuf[1][0], xs);
    #pragma unroll
    for (int q=0;q<4;++q){
        float tbv=prm[512+srow+q];
        #pragma unroll
        for (int tj=0;tj<4;++tj) xl[q][tj]+=gelu_exact(acc[tj][q]+tbv);
    }
    __syncthreads();
    LNSTAGE(256,320); WRITE_XNR();
    __syncthreads();
    MM(xs, &wbuf[2][0]);
    #pragma unroll
    for (int q=0;q<4;++q)
        #pragma unroll
        for (int tj=0;tj<4;++tj) xl[q][tj]+=gelu_exact(acc[tj][q]+prm[576+tj*16+c]);
    __syncthreads();
    LNSTAGE(384,448); WRITE_XNR();
    __syncthreads();
    MM(xs, &wbuf[3][0]);
    __hip_bfloat16* xpo = xpb + (size_t)bn*DD;
    #pragma unroll
    for (int q=0;q<4;++q){
        int s=srow+q;
        if (s<SS){
            #pragma unroll
            for (int tj=0;tj<4;++tj){
                int d=s*HH+tj*16+c;
                hb[d]=xl[q][tj];
                xpo[d]=__float2bfloat16(acc[tj][q]);
            }
        }
    }
#undef LNSTAGE
#undef WRITE_XNP
#undef WRITE_XNR
#undef MM
}

// ---- pack xp bf16 [N][D] -> MFMA-ready [KP/8][D][8] with K zero-pad ----
__global__ __launch_bounds__(256) void k_pack_xp(
    const __hip_bfloat16* __restrict__ xpb, __hip_bfloat16* __restrict__ xpg)
{
    int d = blockIdx.x*256 + threadIdx.x;
    int kc = blockIdx.y; int b = blockIdx.z;
    union { __hip_bfloat16 hv[8]; float4 f4; } u;
    #pragma unroll
    for (int j=0;j<8;++j){
        int k = kc*8+j;
        u.hv[j] = (k<NN) ? xpb[((size_t)b*NN+k)*DD + d] : __float2bfloat16(0.f);
    }
    *reinterpret_cast<float4*>(&xpg[(((size_t)b*(KP/8)+kc)*DD + d)*8]) = u.f4;
}

// ---- spatial bmm via MFMA: h[b] += comb[b] @ xp[b] + sb ----
// 64x128 tile, 4 waves (2x2 of 32x64), 3-buffer depth-2 prefetch, counted vmcnt.
__global__ __launch_bounds__(256,4) void k_bmm_mfma(
    const __hip_bfloat16* __restrict__ combh,
    const __hip_bfloat16* __restrict__ xpg,
    const float* __restrict__ sb,
    float* __restrict__ h,
    __hip_bfloat16* __restrict__ h16,
    int write_h)
{
    __shared__ short As[3][2048];   // [64][32] bf16 per buf (A-swizzled)
    __shared__ short Bs[3][4096];   // [4][128][8] per buf

    int bid = blockIdx.x;
    int wg = (bid & 7)*336 + (bid >> 3);     // bijective XCD-chunked swizzle (2688 = 8*336)
    int bm = wg % 24; int tmp2 = wg / 24; int bd = tmp2 % 28; int b = tmp2 / 28;
    int tid=threadIdx.x, lane=tid&63, w=tid>>6;
    int g=lane>>4, c=lane&15;
    int wr=w>>1, wc=w&1;
    int m0=bm*64, d0=bd*128;

    const char* cb = (const char*)(combh + (size_t)b*MP*KP);
    const char* xb = (const char*)(xpg   + (size_t)b*(KP/8)*(size_t)DD*8);

    // A staging: lane L -> LDS byte L*16 = [row=L>>2][slot=L&3]; data = k-chunk (slot ^ ((row>>1)&3))
    int arow_s = tid>>2, aslot = tid&3;
    int ag = aslot ^ ((arow_s>>1)&3);
    const char* srcA = cb + ((size_t)(m0+arow_s)*KP + ag*8)*2;
    // B staging: two insts cover chunks 0..1 and 2..3
    int bch = tid>>7, bcol = tid&127;
    const char* srcB0 = xb + ((size_t)bch*DD + d0 + bcol)*16;
    const char* srcB1 = xb + ((size_t)(bch+2)*DD + d0 + bcol)*16;
    const size_t BSTEP = (size_t)4*DD*16;

    f32x4 acc[2][4];
    #pragma unroll
    for (int i=0;i<2;++i)
        #pragma unroll
        for (int j=0;j<4;++j) acc[i][j]=(f32x4){0.f,0.f,0.f,0.f};

    // fragment LDS byte offsets
    int aoff[2], boff[4];
    #pragma unroll
    for (int i=0;i<2;++i){
        int row = 32*wr + 16*i + c;
        aoff[i] = row*64 + ((g*16) ^ (((row>>1)&3)<<4));
    }
    #pragma unroll
    for (int j=0;j<4;++j) boff[j] = (g*128 + 64*wc + 16*j + c)*16;

#define STAGE(BUF,T) do { \
    async_load16(srcA  + (size_t)(T)*64,    (char*)As[BUF] + w*1024); \
    async_load16(srcB0 + (size_t)(T)*BSTEP, (char*)Bs[BUF] + w*1024); \
    async_load16(srcB1 + (size_t)(T)*BSTEP, (char*)Bs[BUF] + 4096 + w*1024); } while(0)

    STAGE(0,0); STAGE(1,1);
    asm volatile("s_waitcnt vmcnt(3)" ::: "memory");
    __builtin_amdgcn_s_barrier();

    int cur=0;
    for (int t=0;t<NT;++t){
        if (t+2<NT){
            int nb = cur+2; if (nb>=3) nb-=3;
            STAGE(nb, t+2);
        }
        const char* Ab=(const char*)As[cur];
        const char* Bb=(const char*)Bs[cur];
        bf16x8 af[2], bfv[4];
        #pragma unroll
        for (int i=0;i<2;++i) af[i]=*(const bf16x8*)(Ab + aoff[i]);
        #pragma unroll
        for (int j=0;j<4;++j) bfv[j]=*(const bf16x8*)(Bb + boff[j]);
        #pragma unroll
        for (int i=0;i<2;++i)
            #pragma unroll
            for (int j=0;j<4;++j)
                acc[i][j]=__builtin_amdgcn_mfma_f32_16x16x32_bf16(af[i],bfv[j],acc[i][j],0,0,0);
        if (t+2<NT) asm volatile("s_waitcnt vmcnt(3)" ::: "memory");
        else        asm volatile("s_waitcnt vmcnt(0)" ::: "memory");
        __builtin_amdgcn_s_barrier();
        ++cur; if (cur>=3) cur=0;
    }
#undef STAGE

    // epilogue
    int row_b = m0 + 32*wr + g*4;
    int col_b = d0 + 64*wc + c;
    #pragma unroll
    for (int i=0;i<2;++i){
        #pragma unroll
        for (int q=0;q<4;++q){
            int m = row_b + 16*i + q;
            if (m < NN){
                size_t rb = ((size_t)b*NN+m)*DD;
                size_t fr = ((size_t)b*NN+m)*TOT;
                #pragma unroll
                for (int j=0;j<4;++j){
                    int d = col_b + j*16;
                    float nv = h[rb+d] + acc[i][j][q] + sb[16*j+c];
                    if (write_h) h[rb+d] = nv;
                    if (h16) h16[fr+d] = __float2bfloat16(nv);
                }
            }
        }
    }
}

// ---------------- head GEMM: out = feats16 @ hw16^T + hb ----------------
__global__ __launch_bounds__(256) void k_head_mfma(
    const __hip_bfloat16* __restrict__ feats, const __hip_bfloat16* __restrict__ hw16,
    const float* __restrict__ hb, float* __restrict__ out)
{
    int tid=threadIdx.x, lane=tid&63, w=tid>>6;
    int g=lane>>4, c=lane&15;
    int m0=blockIdx.x*32;
    int rt=w>>1, pt=w&1;
    int arow = m0 + rt*16 + c;
    if (arow > BB*NN-1) arow = BB*NN-1;
    const char* abase = (const char*)feats + (size_t)arow*TOT*2 + g*16;
    const char* bbase = (const char*)hw16 + (size_t)(pt*16+c)*TOT*2 + g*16;
    f32x4 acc=(f32x4){0.f,0.f,0.f,0.f};
    #pragma unroll 4
    for (int kc=0;kc<TOT/32;++kc){
        bf16x8 af =*(const bf16x8*)(abase + (size_t)kc*64);
        bf16x8 bf2=*(const bf16x8*)(bbase + (size_t)kc*64);
        acc=__builtin_amdgcn_mfma_f32_16x16x32_bf16(af,bf2,acc,0,0,0);
    }
    int col = pt*16 + c;
    #pragma unroll
    for (int q=0;q<4;++q){
        int row = m0 + rt*16 + g*4 + q;
        if (row < BB*NN && col < PP)
            out[(size_t)row*PP + col] = acc[q] + hb[col];
    }
}

extern "C" void kernel_launch(void* const* d_in, const int* in_sizes, int n_in,
                              void* d_out, int out_size, void* d_ws, size_t ws_size,
                              hipStream_t stream)
{
    const float* x      = (const float*)d_in[0];
    const float* xfut   = (const float*)d_in[1];
    const float* adj    = (const float*)d_in[2];
    const float* fp_w   = (const float*)d_in[3];
    const float* fp_b   = (const float*)d_in[4];
    const float* inlng  = (const float*)d_in[5];
    const float* inlnb  = (const float*)d_in[6];
    const float* q_w    = (const float*)d_in[7];
    const float* q_b    = (const float*)d_in[8];
    const float* k_w    = (const float*)d_in[9];
    const float* k_b    = (const float*)d_in[10];
    const float* nemb   = (const float*)d_in[11];
    const float* galpha = (const float*)d_in[12];
    const float* wk     = (const float*)d_in[13];
    const float* mk     = (const float*)d_in[14];
    const float* lncg   = (const float*)d_in[15];
    const float* lncb   = (const float*)d_in[16];
    const float* lntg   = (const float*)d_in[17];
    const float* lntb   = (const float*)d_in[18];
    const float* lnfg   = (const float*)d_in[19];
    const float* lnfb   = (const float*)d_in[20];
    const float* lnsg   = (const float*)d_in[21];
    const float* lnsb   = (const float*)d_in[22];
    const float* tw     = (const float*)d_in[23];
    const float* tb     = (const float*)d_in[24];
    const float* fw     = (const float*)d_in[25];
    const float* fb     = (const float*)d_in[26];
    const float* sw     = (const float*)d_in[27];
    const float* sb     = (const float*)d_in[28];
    const float* futw   = (const float*)d_in[29];
    const float* futb   = (const float*)d_in[30];
    const float* hw     = (const float*)d_in[31];
    const float* hb     = (const float*)d_in[32];
    (void)in_sizes; (void)n_in; (void)out_size; (void)ws_size;
    float* out = (float*)d_out;
    float* ws = (float*)d_ws;
    const size_t HSZ = (size_t)BB*NN*SS*HH;

    float* h    = ws;
    float* embn = h + HSZ;
    float* ctx  = embn + (size_t)NN*HH;
    __hip_bfloat16* xpb   = (__hip_bfloat16*)(ctx + (size_t)BB*NN*HH);
    __hip_bfloat16* combh = xpb + HSZ;
    __hip_bfloat16* xpg   = combh + (size_t)BB*MP*KP;
    float* scores = (float*)xpg;   // aliased: scores dead before xpg is written
    unsigned short* wimg  = (unsigned short*)(xpg + (size_t)BB*(KP/8)*(size_t)DD*8);
    unsigned short* qpack = wimg + (size_t)NBLK*WIMG_SZ;
    unsigned short* kpack = qpack + (size_t)BB*8*MP*8;
    __hip_bfloat16* feats16 = (__hip_bfloat16*)(kpack + (size_t)BB*8*MP*8);
    __hip_bfloat16* hw16    = feats16 + (size_t)BB*NN*TOT;

    k_prepw<<<NBLK,256,0,stream>>>(wk, mk, tw, fw, sw, wimg);
    k_prep_head<<<(32*TOT)/256,256,0,stream>>>(hw, hw16);
    k_fut<<<BB*NN,256,0,stream>>>(xfut, futw, futb, feats16);
    k_embnorm<<<NN,64,0,stream>>>(nemb, embn);
    k_front<<<BB*NN,256,0,stream>>>(x, fp_w, fp_b, inlng, inlnb, embn, h, ctx);
    k_qk<<<BB*NN,64,0,stream>>>(ctx, q_w,q_b,k_w,k_b, qpack, kpack);
    dim3 gqkt(MP/128, MP/128, BB);
    k_qkt<<<gqkt,256,0,stream>>>(qpack, kpack, scores);
    dim3 gtop(NN,BB);
    k_topk<<<gtop,256,0,stream>>>(scores, adj, galpha, combh);
    dim3 gpack(DD/256, KP/8, BB);
    for (int i=0;i<NBLK;++i){
        k_mixer2<<<BB*NN,256,0,stream>>>(h, xpb, wimg + (size_t)i*WIMG_SZ,
            lncg+i*HH,lncb+i*HH, lntg+i*HH,lntb+i*HH, lnfg+i*HH,lnfb+i*HH, lnsg+i*HH,lnsb+i*HH,
            tb+i*SS, fb+i*HH);
        k_pack_xp<<<gpack,256,0,stream>>>(xpb, xpg);
        k_bmm_mfma<<<2688,256,0,stream>>>(combh, xpg, sb+i*HH, h,
            (i==NBLK-1) ? feats16 : (__hip_bfloat16*)nullptr,
            (i==NBLK-1) ? 0 : 1);
    }
    k_head_mfma<<<(BB*NN+31)/32,256,0,stream>>>(feats16, hw16, hb, out);
}